// Round 6
// baseline (261.072 us; speedup 1.0000x reference)
//
#include <hip/hip_runtime.h>
#include <math.h>

// Problem constants (fixed by setup_inputs)
#define NROWS 32768   // 32 * 32 * 32
#define DIMS  256
#define KCODES 1024

typedef __attribute__((ext_vector_type(8))) short short8;   // 8 bf16 = 4 VGPRs
typedef __attribute__((ext_vector_type(4))) float f32x4;    // MFMA C/D & stores

// ws layout (float offsets)
static const size_t OFF_WB     = 8388608;                // [1024][256] bf16, MFMA-fragment tile order
static const size_t OFF_WNORM  = OFF_WB + 131072;        // [1024] f32
static const size_t OFF_ENCSUM = OFF_WNORM + 1024;       // [1024]
static const size_t OFF_LOSSP  = OFF_ENCSUM + 1024;      // [1024 used]
static const size_t OFF_WND    = OFF_LOSSP + 8192;       // [1024] f64 (2048 floats), 8B aligned

// out layout (float offsets): loss | quantized NCHW | perplexity | encodings
static const size_t OUT_Q    = 1;
static const size_t OUT_PERP = 8388609;
static const size_t OUT_ENC  = 8388610;

__device__ inline unsigned short f2bf(float f) {
    unsigned int u = __float_as_uint(f);
    unsigned int r = u + 0x7FFFu + ((u >> 16) & 1u);   // RNE
    return (unsigned short)(r >> 16);
}

// pack distance (fp32, low 10 mantissa bits cleared) with 10-bit code index.
__device__ inline float packdi(float d, int code) {
    return __uint_as_float((__float_as_uint(d) & 0xFFFFFC00u) | (unsigned)code);
}

// async global->LDS copy, 16B per lane (wave-uniform LDS base + lane*16)
__device__ __forceinline__ void gl_lds16(const void* gsrc, void* ldst) {
    typedef const __attribute__((address_space(1))) unsigned int GU;
    typedef __attribute__((address_space(3))) unsigned int LU;
    __builtin_amdgcn_global_load_lds((GU*)gsrc, (LU*)ldst, 16, 0, 0);
}

// ---------------- W prep: bf16 fragment-order layout + wnorm (f32+f64) ----
__global__ __launch_bounds__(256) void wprep(const float* __restrict__ Wm,
                                             unsigned short* __restrict__ Wb,
                                             float* __restrict__ wnorm,
                                             double* __restrict__ wnormd,
                                             float* __restrict__ enc_sum)
{
    const int r = blockIdx.x * 4 + (threadIdx.x >> 6);
    const int lane = threadIdx.x & 63;
    float4 v = ((const float4*)(Wm + (size_t)r * 256))[lane];
    ushort4 o;
    o.x = f2bf(v.x); o.y = f2bf(v.y); o.z = f2bf(v.z); o.w = f2bf(v.w);
    const int d0 = lane * 4;
    const int kk = d0 >> 5, quad = (d0 >> 3) & 3, jb = d0 & 7;
    const int tt = r >> 4, col = r & 15;
    const size_t idx = (size_t)tt * 4096 + (size_t)((kk * 4 + quad) * 16 + col) * 8 + jb;
    *(ushort4*)(Wb + idx) = o;
    double s = (double)v.x*(double)v.x + (double)v.y*(double)v.y
             + (double)v.z*(double)v.z + (double)v.w*(double)v.w;
    #pragma unroll
    for (int off = 32; off > 0; off >>= 1) s += __shfl_down(s, off);
    if (lane == 0) { wnormd[r] = s; wnorm[r] = (float)s; }
    if (blockIdx.x == 0) {
        #pragma unroll
        for (int q = 0; q < 4; ++q) enc_sum[threadIdx.x * 4 + q] = 0.0f;
    }
}

// ---------------- fused MFMA GEMM + top-k + fp64 refine + enc + quantize + loss ----
// 256 thr = 4 waves, 32 rows/block, grid 1024.
// Main loop: depth-2 software pipeline (T3+T4): triple-buffered B tiles
// (3 x 16KB), tile cc+2 issued at top of iter cc, counted s_waitcnt vmcnt(4)
// + raw s_barrier (prefetch stays in flight across barriers; no vmcnt(0)
// drain). Loop contains NO other vmem: wnorm is staged to LDS in prologue.
// Mappings:
//   MFMA:   wave w: g=w&1 (16-row group), h=w>>1 (512-code half); lane: col,quad
//   refine: row = t>>3 (0..31), q8 = t&7 (two 16-dim slices: q8*16 & 128+q8*16)
// enc + outq use plain stores (complete at L2; HBM eviction drains async).
__global__ __launch_bounds__(256, 3) void gemm_topk_quant(
    const float* __restrict__ x, const unsigned short* __restrict__ Wb,
    const float* __restrict__ wnorm, const double* __restrict__ wnd,
    const float* __restrict__ Wm,
    float* __restrict__ enc_sum,
    float* __restrict__ enc,
    float* __restrict__ outq, float* __restrict__ loss_part)
{
    __shared__ __align__(16) char lds[53248];
    // loop: buf k = lds + k*16384, k=0..2 (48 KB); wnLds @ 49152 (4 KB)
    // post-loop aliases (phases separated by barriers):
    float*  sCd   = (float*)lds;                 // [96][34] f32 = 13056 B (dump->merge)
    int*    mIdx  = (int*)(lds + 13312);         // [256] -> 14336
    double* rd    = (double*)(lds + 14336);      // [256] f64 -> 16384
    float*  qtile = (float*)lds;                 // [32][132] f32 = 16896 B (epilogue)
    double* rnr   = (double*)(lds + 16896);      // [32] f64 -> 17152
    int*    s0    = (int*)(lds + 17152);         // [32]
    int*    s1    = (int*)(lds + 17280);         // [32]
    float*  sw0   = (float*)(lds + 17408);       // [32]
    float*  sw1   = (float*)(lds + 17536);       // [32]
    double* sredd = (double*)(lds + 17664);      // [4]
    unsigned short* xtile = (unsigned short*)(lds + 32768);  // [32][256] bf16 swizzled, pre-loop (buf2)
    float*  wnLds = (float*)(lds + 49152);       // [1024] f32

    const int t    = threadIdx.x;
    const int wave = t >> 6;
    const int g    = wave & 1;
    const int h    = wave >> 1;
    const int lane = t & 63;
    const int col  = lane & 15;
    const int quad = lane >> 4;
    const int r0   = blockIdx.x * 32;
    const int b    = r0 >> 10;
    const int hw0  = r0 & 1023;
    const float* xblk = x + (size_t)b * 262144 + hw0;   // + d*1024 + hw_local

    const int row = t >> 3;   // refine/epilogue row (hw local), 0..31
    const int q8  = t & 7;    // dim-slice

    // ---- xs: this thread's 32 x values — issue FIRST (oldest vmcnt slots) ----
    float xs[32];
    {
        const float* xr = xblk + row;
        #pragma unroll
        for (int p2 = 0; p2 < 2; ++p2)
            #pragma unroll
            for (int j = 0; j < 16; ++j)
                xs[p2 * 16 + j] = xr[(size_t)(p2 * 128 + q8 * 16 + j) * 1024];
    }

    // ---- prologue staging: T0 -> buf0, T1 -> buf1, wnorm -> wnLds ----
    const char* wb_bytes = (const char*)Wb;
    {
        const char* s0p = wb_bytes + (size_t)(h * 32 + 0) * 8192 + g * 4096;
        const char* s1p = wb_bytes + (size_t)(h * 32 + 1) * 8192 + g * 4096;
        char* d0p = lds + 0 * 16384 + h * 8192 + g * 4096;
        char* d1p = lds + 1 * 16384 + h * 8192 + g * 4096;
        #pragma unroll
        for (int q = 0; q < 4; ++q) {
            gl_lds16(s0p + q * 1024 + lane * 16, d0p + q * 1024);
            gl_lds16(s1p + q * 1024 + lane * 16, d1p + q * 1024);
        }
        // wnorm: wave w stages 1 KB
        gl_lds16((const char*)wnorm + wave * 1024 + lane * 16,
                 (char*)wnLds + wave * 1024);
    }

    // ---- build bf16 x-tile [32][256] in LDS (buf2) from xs ----
    // XOR-swizzle 16B unit with row&7 to spread banks.
    #pragma unroll
    for (int p2 = 0; p2 < 2; ++p2)
        #pragma unroll
        for (int j4 = 0; j4 < 4; ++j4) {
            ushort4 o;
            o.x = f2bf(xs[p2 * 16 + j4 * 4 + 0]);
            o.y = f2bf(xs[p2 * 16 + j4 * 4 + 1]);
            o.z = f2bf(xs[p2 * 16 + j4 * 4 + 2]);
            o.w = f2bf(xs[p2 * 16 + j4 * 4 + 3]);
            const int xi = (row * 256 + p2 * 128 + q8 * 16 + j4 * 4) ^ ((row & 7) << 3);
            *(ushort4*)(xtile + xi) = o;
        }
    __syncthreads();   // full drain (prologue only): xtile + T0/T1 + wnLds visible

    // ---- A fragments from x-tile (rows g*16..g*16+15) ----
    short8 af[8];
    #pragma unroll
    for (int kk = 0; kk < 8; ++kk) {
        const int xi = ((g * 16 + col) * 256 + kk * 32 + quad * 8) ^ ((col & 7) << 3);
        af[kk] = *(const short8*)(xtile + xi);
    }
    __syncthreads();   // af reads done; buf2 free for T2

    float m0[4], m1[4], m2[4];
    #pragma unroll
    for (int r = 0; r < 4; ++r) { m0[r] = 3.4e38f; m1[r] = 3.4e38f; m2[r] = 3.4e38f; }

    // ---- main loop: depth-2 pipeline, counted vmcnt, raw barriers ----
    int bi = 0;   // buffer holding tile cc
    int bj = 2;   // buffer receiving tile cc+2
    for (int cc = 0; cc < 32; ++cc) {
        if (cc < 30) {
            const char* src = wb_bytes + (size_t)(h * 32 + cc + 2) * 8192 + g * 4096;
            char* dstl = lds + bj * 16384 + h * 8192 + g * 4096;
            #pragma unroll
            for (int q = 0; q < 4; ++q)
                gl_lds16(src + q * 1024 + lane * 16, dstl + q * 1024);
        }
        const char* bb = lds + bi * 16384 + h * 8192;
        f32x4 acc = {0.f, 0.f, 0.f, 0.f};
        #pragma unroll
        for (int kk = 0; kk < 8; ++kk) {
            short8 b0 = *(const short8*)(bb + kk * 1024 + lane * 16);
            acc = __builtin_amdgcn_mfma_f32_16x16x32_bf16(af[kk], b0, acc, 0, 0, 0);
        }
        const int code0 = h * 512 + cc * 16 + col;
        const float wn0 = wnLds[code0];            // LDS read: no vmcnt pollution
        #pragma unroll
        for (int r = 0; r < 4; ++r) {
            float pv0 = packdi(fmaf(-2.0f, acc[r], wn0), code0);
            float t0  = fmaxf(m0[r], pv0); m0[r] = fminf(m0[r], pv0);
            float t1  = fmaxf(m1[r], t0);  m1[r] = fminf(m1[r], t0);
            m2[r] = fminf(m2[r], t1);
        }
        __builtin_amdgcn_sched_barrier(0);
        if (cc < 30) {
            asm volatile("s_waitcnt vmcnt(4)" ::: "memory");   // tile cc+1 resident; cc+2 in flight
        } else if (cc == 30) {
            asm volatile("s_waitcnt vmcnt(0)" ::: "memory");   // tile 31 resident
        }
        __builtin_amdgcn_s_barrier();
        __builtin_amdgcn_sched_barrier(0);
        bi = (bi == 2) ? 0 : bi + 1;
        bj = (bj == 2) ? 0 : bj + 1;
    }

    // ---- dump per-lane candidates, transposed layout [96 slots][34 rows] ----
    #pragma unroll
    for (int r = 0; r < 4; ++r) {
        const int rl = g * 16 + quad * 4 + r;
        const int s  = h * 48 + col * 3;
        sCd[(s + 0) * 34 + rl] = m0[r];
        sCd[(s + 1) * 34 + rl] = m1[r];
        sCd[(s + 2) * 34 + rl] = m2[r];
    }
    __syncthreads();

    // ---- parallel exact top-8 merge: 8 threads/row, 12 slots each ----
    {
        float a0 = 3.4e38f, a1 = 3.4e38f, a2 = 3.4e38f, a3 = 3.4e38f,
              a4 = 3.4e38f, a5 = 3.4e38f, a6 = 3.4e38f, a7 = 3.4e38f;
        #pragma unroll
        for (int i = 0; i < 12; ++i) {
            float d = sCd[(q8 * 12 + i) * 34 + row];
            if (d < a7) {
                a7 = d; float tf;
                if (a7 < a6) { tf = a7; a7 = a6; a6 = tf; }
                if (a6 < a5) { tf = a6; a6 = a5; a5 = tf; }
                if (a5 < a4) { tf = a5; a5 = a4; a4 = tf; }
                if (a4 < a3) { tf = a4; a4 = a3; a3 = tf; }
                if (a3 < a2) { tf = a3; a3 = a2; a2 = tf; }
                if (a2 < a1) { tf = a2; a2 = a1; a1 = tf; }
                if (a1 < a0) { tf = a1; a1 = a0; a0 = tf; }
            }
        }
        // 8 rounds: global min of the 8 heads (values unique via packed code bits)
        float sel = 3.4e38f;
        #pragma unroll
        for (int q = 0; q < 8; ++q) {
            float m = a0;
            m = fminf(m, __shfl_xor(m, 1));
            m = fminf(m, __shfl_xor(m, 2));
            m = fminf(m, __shfl_xor(m, 4));
            if (q8 == q) sel = m;
            if (a0 == m) { a0 = a1; a1 = a2; a2 = a3; a3 = a4;
                           a4 = a5; a5 = a6; a6 = a7; a7 = 3.4e38f; }
        }
        mIdx[row * 8 + q8] = (int)(__float_as_uint(sel) & 1023u);
    }
    __syncthreads();

    // ---- fp64 refine from xs regs: partial dots per slice, shfl_xor reduce ----
    {
        int cd[8];
        #pragma unroll
        for (int c8 = 0; c8 < 8; ++c8) cd[c8] = mIdx[row * 8 + c8];
        double dot[8];
        #pragma unroll
        for (int c8 = 0; c8 < 8; ++c8) dot[c8] = 0.0;
        double rn = 0.0;
        #pragma unroll
        for (int v = 0; v < 8; ++v) {
            const int d0 = (v >> 2) * 128 + q8 * 16 + (v & 3) * 4;
            const double x0 = (double)xs[v * 4 + 0];
            const double x1 = (double)xs[v * 4 + 1];
            const double x2 = (double)xs[v * 4 + 2];
            const double x3 = (double)xs[v * 4 + 3];
            rn += x0*x0 + x1*x1 + x2*x2 + x3*x3;
            #pragma unroll
            for (int c8 = 0; c8 < 8; ++c8) {
                const float4 wv = *(const float4*)(Wm + (size_t)cd[c8] * 256 + d0);
                dot[c8] += x0 * (double)wv.x + x1 * (double)wv.y
                         + x2 * (double)wv.z + x3 * (double)wv.w;
            }
        }
        #pragma unroll
        for (int m = 1; m < 8; m <<= 1) {
            #pragma unroll
            for (int c8 = 0; c8 < 8; ++c8) dot[c8] += __shfl_xor(dot[c8], m);
            rn += __shfl_xor(rn, m);
        }
        // static select of this thread's candidate (avoid dynamic reg indexing)
        int myc = 0; double mydot = 0.0;
        #pragma unroll
        for (int c8 = 0; c8 < 8; ++c8)
            if (q8 == c8) { myc = cd[c8]; mydot = dot[c8]; }
        rd[row * 8 + q8] = wnd[myc] - 2.0 * mydot;
        if (q8 == 0) rnr[row] = rn;
    }
    __syncthreads();

    // ---- final per-row top-2 (exact), weights ----
    if (t < 32) {
        double rn = rnr[t];
        double d0 = 1e300, d1 = 1e300; int b0 = 1 << 30, b1 = 1 << 30;
        #pragma unroll
        for (int q = 0; q < 8; ++q) {
            double d = rd[t * 8 + q];
            int    c = mIdx[t * 8 + q];
            if (d < d0 || (d == d0 && c < b0)) { d1 = d0; b1 = b0; d0 = d; b0 = c; }
            else if (d < d1 || (d == d1 && c < b1)) { d1 = d; b1 = c; }
        }
        double D0 = rn + d0;
        double D1 = rn + d1;
        double inv0 = 1.0 / D0, inv1 = 1.0 / D1;
        double nrm = sqrt(inv0 * inv0 + inv1 * inv1);
        if (nrm < 1e-12) nrm = 1e-12;
        float w0 = (float)(inv0 / nrm);
        float w1 = (float)(inv1 / nrm);
        s0[t] = b0; s1[t] = b1; sw0[t] = w0; sw1[t] = w1;
        atomicAdd(&enc_sum[b0], w0);
        atomicAdd(&enc_sum[b1], w1);
    }
    __syncthreads();

    // ---- encodings rows: wave w writes rows w*8..w*8+7, coalesced stores ----
    // plain stores: complete at L2, HBM eviction drains asynchronously
    #pragma unroll
    for (int rr = 0; rr < 8; ++rr) {
        const int rw = wave * 8 + rr;
        const int i0 = s0[rw], i1 = s1[rw];
        const float w0 = sw0[rw], w1 = sw1[rw];
        f32x4* dst = (f32x4*)(enc + (size_t)(r0 + rw) * KCODES);
        #pragma unroll
        for (int it = 0; it < 4; ++it) {
            const int base = it * 256 + lane * 4;
            f32x4 v;
            v.x = (base + 0 == i0) ? w0 : ((base + 0 == i1) ? w1 : 0.0f);
            v.y = (base + 1 == i0) ? w0 : ((base + 1 == i1) ? w1 : 0.0f);
            v.z = (base + 2 == i0) ? w0 : ((base + 2 == i1) ? w1 : 0.0f);
            v.w = (base + 3 == i0) ? w0 : ((base + 3 == i1) ? w1 : 0.0f);
            dst[it * 64 + lane] = v;
        }
    }

    // ---- quantize + loss (from xs) + NCHW write, 2 chunks of 128 channels ----
    double ls = 0.0;
    #pragma unroll
    for (int p2 = 0; p2 < 2; ++p2) {
        const int   cA = s0[row], cB = s1[row];
        const float w0 = sw0[row], w1 = sw1[row];
        const float* W0 = Wm + (size_t)cA * 256 + p2 * 128 + q8 * 16;
        const float* W1 = Wm + (size_t)cB * 256 + p2 * 128 + q8 * 16;
        #pragma unroll
        for (int v4 = 0; v4 < 4; ++v4) {
            const float4 a  = *(const float4*)(W0 + v4 * 4);
            const float4 bv = *(const float4*)(W1 + v4 * 4);
            f32x4 qv;
            qv.x = w0 * a.x + w1 * bv.x;
            qv.y = w0 * a.y + w1 * bv.y;
            qv.z = w0 * a.z + w1 * bv.z;
            qv.w = w0 * a.w + w1 * bv.w;
            float e0 = qv.x - xs[p2 * 16 + v4 * 4 + 0];
            float e1 = qv.y - xs[p2 * 16 + v4 * 4 + 1];
            float e2 = qv.z - xs[p2 * 16 + v4 * 4 + 2];
            float e3 = qv.w - xs[p2 * 16 + v4 * 4 + 3];
            ls += (double)(e0*e0 + e1*e1 + e2*e2 + e3*e3);
            const int dl = q8 * 16 + v4 * 4;
            *(f32x4*)(qtile + row * 132 + dl) = qv;
        }
        __syncthreads();
        #pragma unroll
        for (int p = 0; p < 4; ++p) {
            const int task = p * 256 + t;
            const int cl   = task >> 3;       // channel-local 0..127
            const int hwq  = task & 7;
            f32x4 v;
            v.x = qtile[(hwq * 4 + 0) * 132 + cl];
            v.y = qtile[(hwq * 4 + 1) * 132 + cl];
            v.z = qtile[(hwq * 4 + 2) * 132 + cl];
            v.w = qtile[(hwq * 4 + 3) * 132 + cl];
            *(f32x4*)(outq + ((size_t)(b * 256 + p2 * 128 + cl)) * 1024 + hw0 + hwq * 4) = v;
        }
        __syncthreads();
    }

    // ---- block loss partial ----
    #pragma unroll
    for (int off = 32; off > 0; off >>= 1) ls += __shfl_down(ls, off);
    if (lane == 0) sredd[wave] = ls;
    __syncthreads();
    if (t == 0) {
        double s = 0.0;
        #pragma unroll
        for (int w = 0; w < 4; ++w) s += sredd[w];
        loss_part[blockIdx.x] = (float)s;
    }
}

// ---------------- finalize: loss + perplexity ----------------
__global__ __launch_bounds__(256) void finalize_k(const float* __restrict__ enc_sum,
                                                  const float* __restrict__ loss_part,
                                                  float* __restrict__ out)
{
    __shared__ double sh[256];
    const int t = threadIdx.x;
    double ls = 0.0;
    for (int i = t; i < 1024; i += 256) ls += (double)loss_part[i];
    sh[t] = ls; __syncthreads();
    for (int s = 128; s > 0; s >>= 1) { if (t < s) sh[t] += sh[t + s]; __syncthreads(); }
    double loss_sum = sh[0];
    __syncthreads();
    double ps = 0.0;
    for (int k = t; k < KCODES; k += 256) {
        double p = (double)enc_sum[k] / (double)NROWS;
        ps += p * log(p + 1e-10);
    }
    sh[t] = ps; __syncthreads();
    for (int s = 128; s > 0; s >>= 1) { if (t < s) sh[t] += sh[t + s]; __syncthreads(); }
    if (t == 0) {
        out[0]        = (float)(1.25 * loss_sum / 8388608.0);
        out[OUT_PERP] = (float)exp(-sh[0]);
    }
}

extern "C" void kernel_launch(void* const* d_in, const int* in_sizes, int n_in,
                              void* d_out, int out_size, void* d_ws, size_t ws_size,
                              hipStream_t stream)
{
    const float* x  = (const float*)d_in[0];
    const float* Wm = (const float*)d_in[1];
    float* out = (float*)d_out;
    float* ws  = (float*)d_ws;

    unsigned short* Wb      = (unsigned short*)(ws + OFF_WB);
    float*          wnorm   = ws + OFF_WNORM;
    float*          enc_sum = ws + OFF_ENCSUM;
    float*          loss_p  = ws + OFF_LOSSP;
    double*         wnd     = (double*)(ws + OFF_WND);

    wprep<<<KCODES / 4, 256, 0, stream>>>(Wm, Wb, wnorm, wnd, enc_sum);
    gemm_topk_quant<<<NROWS / 32, 256, 0, stream>>>(x, Wb, wnorm, wnd, Wm, enc_sum,
                                                    out + OUT_ENC, out + OUT_Q, loss_p);
    finalize_k<<<1, 256, 0, stream>>>(enc_sum, loss_p, out);
}

// Round 7
// 253.694 us; speedup vs baseline: 1.0291x; 1.0291x over previous
//
#include <hip/hip_runtime.h>
#include <math.h>

// Problem constants (fixed by setup_inputs)
#define NROWS 32768   // 32 * 32 * 32
#define DIMS  256
#define KCODES 1024

typedef __attribute__((ext_vector_type(8))) short short8;   // 8 bf16 = 4 VGPRs
typedef __attribute__((ext_vector_type(4))) float f32x4;    // MFMA C/D & stores

// ws layout (float offsets)
static const size_t OFF_WB     = 8388608;                // [1024][256] bf16, MFMA-fragment tile order
static const size_t OFF_WNORM  = OFF_WB + 131072;        // [1024] f32
static const size_t OFF_ENCSUM = OFF_WNORM + 1024;       // [1024]
static const size_t OFF_LOSSP  = OFF_ENCSUM + 1024;      // [1024 used]
static const size_t OFF_WND    = OFF_LOSSP + 8192;       // [1024] f64 (2048 floats), 8B aligned

// out layout (float offsets): loss | quantized NCHW | perplexity | encodings
static const size_t OUT_Q    = 1;
static const size_t OUT_PERP = 8388609;
static const size_t OUT_ENC  = 8388610;

__device__ inline unsigned short f2bf(float f) {
    unsigned int u = __float_as_uint(f);
    unsigned int r = u + 0x7FFFu + ((u >> 16) & 1u);   // RNE
    return (unsigned short)(r >> 16);
}

// pack distance (fp32, low 10 mantissa bits cleared) with 10-bit code index.
__device__ inline float packdi(float d, int code) {
    return __uint_as_float((__float_as_uint(d) & 0xFFFFFC00u) | (unsigned)code);
}

// async global->LDS copy, 16B per lane (wave-uniform LDS base + lane*16)
__device__ __forceinline__ void gl_lds16(const void* gsrc, void* ldst) {
    typedef const __attribute__((address_space(1))) unsigned int GU;
    typedef __attribute__((address_space(3))) unsigned int LU;
    __builtin_amdgcn_global_load_lds((GU*)gsrc, (LU*)ldst, 16, 0, 0);
}

// ---------------- W prep: bf16 fragment-order layout + wnorm (f32+f64) ----
__global__ __launch_bounds__(256) void wprep(const float* __restrict__ Wm,
                                             unsigned short* __restrict__ Wb,
                                             float* __restrict__ wnorm,
                                             double* __restrict__ wnormd,
                                             float* __restrict__ enc_sum)
{
    const int r = blockIdx.x * 4 + (threadIdx.x >> 6);
    const int lane = threadIdx.x & 63;
    float4 v = ((const float4*)(Wm + (size_t)r * 256))[lane];
    ushort4 o;
    o.x = f2bf(v.x); o.y = f2bf(v.y); o.z = f2bf(v.z); o.w = f2bf(v.w);
    const int d0 = lane * 4;
    const int kk = d0 >> 5, quad = (d0 >> 3) & 3, jb = d0 & 7;
    const int tt = r >> 4, col = r & 15;
    const size_t idx = (size_t)tt * 4096 + (size_t)((kk * 4 + quad) * 16 + col) * 8 + jb;
    *(ushort4*)(Wb + idx) = o;
    double s = (double)v.x*(double)v.x + (double)v.y*(double)v.y
             + (double)v.z*(double)v.z + (double)v.w*(double)v.w;
    #pragma unroll
    for (int off = 32; off > 0; off >>= 1) s += __shfl_down(s, off);
    if (lane == 0) { wnormd[r] = s; wnorm[r] = (float)s; }
    if (blockIdx.x == 0) {
        #pragma unroll
        for (int q = 0; q < 4; ++q) enc_sum[threadIdx.x * 4 + q] = 0.0f;
    }
}

// ---------------- fused MFMA GEMM + top-k + fp64 refine + enc + quantize + loss ----
// 256 thr = 4 waves, 32 rows/block, grid 1024, LDS 36 KB -> 4 blocks/CU.
// Mappings:
//   MFMA:   wave w: g=w&1 (16-row group), h=w>>1 (512-code half); lane: col,quad
//   refine: row = t>>3 (0..31), q8 = t&7 (two 16-dim slices: q8*16 & 128+q8*16)
// Main loop (32 iters): dbuf 2x16KB staged via global_load_lds; split 4+4 MFMA
// chains for ILP; med3-based exact top-3 insert (3 VALU); iteration cc also
// zero-streams encodings row r0+cc (coalesced 4KB) so the 128MB enc output
// drains inside the loop. After top-2, 2 scalar stores/row patch the weights.
__global__ __launch_bounds__(256, 4) void gemm_topk_quant(
    const float* __restrict__ x, const unsigned short* __restrict__ Wb,
    const float* __restrict__ wnorm, const double* __restrict__ wnd,
    const float* __restrict__ Wm,
    float* __restrict__ enc_sum,
    float* __restrict__ enc,
    float* __restrict__ outq, float* __restrict__ loss_part)
{
    __shared__ __align__(16) char lds[36864];
    // loop: buf0 = lds[0,16K), buf1 = lds[16K,32K); wnLds @ 32K (4 KB)
    // post-loop aliases (phases separated by barriers):
    float*  sCd   = (float*)lds;                 // [96][34] f32 = 13056 B (dump->merge)
    int*    mIdx  = (int*)(lds + 13312);         // [256] -> 14336
    double* rd    = (double*)(lds + 14336);      // [256] f64 -> 16384
    float*  qtile = (float*)lds;                 // [32][132] f32 = 16896 B (epilogue)
    double* rnr   = (double*)(lds + 16896);      // [32] f64 -> 17152
    int*    s0    = (int*)(lds + 17152);         // [32]
    int*    s1    = (int*)(lds + 17280);         // [32]
    float*  sw0   = (float*)(lds + 17408);       // [32]
    float*  sw1   = (float*)(lds + 17536);       // [32]
    double* sredd = (double*)(lds + 17664);      // [4]
    unsigned short* xtile = (unsigned short*)(lds + 16384);  // [32][256] bf16 swizzled, pre-loop
    float*  wnLds = (float*)(lds + 32768);       // [1024] f32

    const int t    = threadIdx.x;
    const int wave = t >> 6;
    const int g    = wave & 1;
    const int h    = wave >> 1;
    const int lane = t & 63;
    const int col  = lane & 15;
    const int quad = lane >> 4;
    const int r0   = blockIdx.x * 32;
    const int b    = r0 >> 10;
    const int hw0  = r0 & 1023;
    const float* xblk = x + (size_t)b * 262144 + hw0;   // + d*1024 + hw_local

    const int row = t >> 3;   // refine/epilogue row (hw local), 0..31
    const int q8  = t & 7;    // dim-slice

    // ---- issue prologue B staging (cc=0 -> buf0) + wnorm -> wnLds first ----
    const char* wb_bytes = (const char*)Wb;
    {
        const char* src = wb_bytes + (size_t)(h * 32) * 8192 + g * 4096;
        char* dstl = lds + h * 8192 + g * 4096;
        #pragma unroll
        for (int q = 0; q < 4; ++q)
            gl_lds16(src + q * 1024 + lane * 16, dstl + q * 1024);
        gl_lds16((const char*)wnorm + wave * 1024 + lane * 16,
                 (char*)wnLds + wave * 1024);
    }

    // ---- xs: this thread's 32 x values (row, dims p2*128 + q8*16 + j) ----
    float xs[32];
    {
        const float* xr = xblk + row;
        #pragma unroll
        for (int p2 = 0; p2 < 2; ++p2)
            #pragma unroll
            for (int j = 0; j < 16; ++j)
                xs[p2 * 16 + j] = xr[(size_t)(p2 * 128 + q8 * 16 + j) * 1024];
    }

    // ---- build bf16 x-tile [32][256] in LDS (buf1 alias) from xs ----
    // XOR-swizzle 16B unit with row&7 to spread banks.
    #pragma unroll
    for (int p2 = 0; p2 < 2; ++p2)
        #pragma unroll
        for (int j4 = 0; j4 < 4; ++j4) {
            ushort4 o;
            o.x = f2bf(xs[p2 * 16 + j4 * 4 + 0]);
            o.y = f2bf(xs[p2 * 16 + j4 * 4 + 1]);
            o.z = f2bf(xs[p2 * 16 + j4 * 4 + 2]);
            o.w = f2bf(xs[p2 * 16 + j4 * 4 + 3]);
            const int xi = (row * 256 + p2 * 128 + q8 * 16 + j4 * 4) ^ ((row & 7) << 3);
            *(ushort4*)(xtile + xi) = o;
        }
    __syncthreads();

    // ---- A fragments from x-tile (rows g*16..g*16+15) ----
    short8 af[8];
    #pragma unroll
    for (int kk = 0; kk < 8; ++kk) {
        const int xi = ((g * 16 + col) * 256 + kk * 32 + quad * 8) ^ ((col & 7) << 3);
        af[kk] = *(const short8*)(xtile + xi);
    }
    __syncthreads();   // af reads done; buf0+wnLds staged. cc=0 may overwrite xtile.

    float m0[4], m1[4], m2[4];
    #pragma unroll
    for (int r = 0; r < 4; ++r) { m0[r] = 3.4e38f; m1[r] = 3.4e38f; m2[r] = 3.4e38f; }

    const f32x4 zero4 = {0.f, 0.f, 0.f, 0.f};
    for (int cc = 0; cc < 32; ++cc) {
        if (cc < 31) {
            const char* src = wb_bytes + (size_t)(h * 32 + cc + 1) * 8192 + g * 4096;
            char* dstl = lds + ((cc + 1) & 1) * 16384 + h * 8192 + g * 4096;
            #pragma unroll
            for (int q = 0; q < 4; ++q)
                gl_lds16(src + q * 1024 + lane * 16, dstl + q * 1024);
        }
        // zero-stream one encodings row per iteration (coalesced 4 KB)
        *(f32x4*)(enc + (size_t)(r0 + cc) * KCODES + t * 4) = zero4;

        const char* bb = lds + (cc & 1) * 16384 + h * 8192;
        f32x4 acc_a = {0.f, 0.f, 0.f, 0.f};
        f32x4 acc_b = {0.f, 0.f, 0.f, 0.f};
        #pragma unroll
        for (int kk = 0; kk < 4; ++kk) {
            short8 b0 = *(const short8*)(bb + kk * 1024 + lane * 16);
            short8 b1 = *(const short8*)(bb + (kk + 4) * 1024 + lane * 16);
            acc_a = __builtin_amdgcn_mfma_f32_16x16x32_bf16(af[kk], b0, acc_a, 0, 0, 0);
            acc_b = __builtin_amdgcn_mfma_f32_16x16x32_bf16(af[kk + 4], b1, acc_b, 0, 0, 0);
        }
        const int code0 = h * 512 + cc * 16 + col;
        const float wn0 = wnLds[code0];
        #pragma unroll
        for (int r = 0; r < 4; ++r) {
            float pv0 = packdi(fmaf(-2.0f, acc_a[r] + acc_b[r], wn0), code0);
            // exact sorted-3 insert via med3 (3 ops)
            m2[r] = __builtin_amdgcn_fmed3f(m1[r], m2[r], pv0);
            m1[r] = __builtin_amdgcn_fmed3f(m0[r], m1[r], pv0);
            m0[r] = fminf(m0[r], pv0);
        }
        __syncthreads();   // staged data for cc+1 visible; buf[cc&1] reads done
    }

    // ---- dump per-lane candidates, transposed layout [96 slots][34 rows] ----
    #pragma unroll
    for (int r = 0; r < 4; ++r) {
        const int rl = g * 16 + quad * 4 + r;
        const int s  = h * 48 + col * 3;
        sCd[(s + 0) * 34 + rl] = m0[r];
        sCd[(s + 1) * 34 + rl] = m1[r];
        sCd[(s + 2) * 34 + rl] = m2[r];
    }
    __syncthreads();

    // ---- parallel exact top-8 merge: 8 threads/row, 12 slots each ----
    {
        float a0 = 3.4e38f, a1 = 3.4e38f, a2 = 3.4e38f, a3 = 3.4e38f,
              a4 = 3.4e38f, a5 = 3.4e38f, a6 = 3.4e38f, a7 = 3.4e38f;
        #pragma unroll
        for (int i = 0; i < 12; ++i) {
            float d = sCd[(q8 * 12 + i) * 34 + row];
            if (d < a7) {
                a7 = d; float tf;
                if (a7 < a6) { tf = a7; a7 = a6; a6 = tf; }
                if (a6 < a5) { tf = a6; a6 = a5; a5 = tf; }
                if (a5 < a4) { tf = a5; a5 = a4; a4 = tf; }
                if (a4 < a3) { tf = a4; a4 = a3; a3 = tf; }
                if (a3 < a2) { tf = a3; a3 = a2; a2 = tf; }
                if (a2 < a1) { tf = a2; a2 = a1; a1 = tf; }
                if (a1 < a0) { tf = a1; a1 = a0; a0 = tf; }
            }
        }
        // 8 rounds: global min of the 8 heads (values unique via packed code bits)
        float sel = 3.4e38f;
        #pragma unroll
        for (int q = 0; q < 8; ++q) {
            float m = a0;
            m = fminf(m, __shfl_xor(m, 1));
            m = fminf(m, __shfl_xor(m, 2));
            m = fminf(m, __shfl_xor(m, 4));
            if (q8 == q) sel = m;
            if (a0 == m) { a0 = a1; a1 = a2; a2 = a3; a3 = a4;
                           a4 = a5; a5 = a6; a6 = a7; a7 = 3.4e38f; }
        }
        mIdx[row * 8 + q8] = (int)(__float_as_uint(sel) & 1023u);
    }
    __syncthreads();

    // ---- fp64 refine from xs regs: partial dots per slice, shfl_xor reduce ----
    {
        int cd[8];
        #pragma unroll
        for (int c8 = 0; c8 < 8; ++c8) cd[c8] = mIdx[row * 8 + c8];
        double dot[8];
        #pragma unroll
        for (int c8 = 0; c8 < 8; ++c8) dot[c8] = 0.0;
        double rn = 0.0;
        #pragma unroll
        for (int v = 0; v < 8; ++v) {
            const int d0 = (v >> 2) * 128 + q8 * 16 + (v & 3) * 4;
            const double x0 = (double)xs[v * 4 + 0];
            const double x1 = (double)xs[v * 4 + 1];
            const double x2 = (double)xs[v * 4 + 2];
            const double x3 = (double)xs[v * 4 + 3];
            rn += x0*x0 + x1*x1 + x2*x2 + x3*x3;
            #pragma unroll
            for (int c8 = 0; c8 < 8; ++c8) {
                const float4 wv = *(const float4*)(Wm + (size_t)cd[c8] * 256 + d0);
                dot[c8] += x0 * (double)wv.x + x1 * (double)wv.y
                         + x2 * (double)wv.z + x3 * (double)wv.w;
            }
        }
        #pragma unroll
        for (int m = 1; m < 8; m <<= 1) {
            #pragma unroll
            for (int c8 = 0; c8 < 8; ++c8) dot[c8] += __shfl_xor(dot[c8], m);
            rn += __shfl_xor(rn, m);
        }
        // static select of this thread's candidate (avoid dynamic reg indexing)
        int myc = 0; double mydot = 0.0;
        #pragma unroll
        for (int c8 = 0; c8 < 8; ++c8)
            if (q8 == c8) { myc = cd[c8]; mydot = dot[c8]; }
        rd[row * 8 + q8] = wnd[myc] - 2.0 * mydot;
        if (q8 == 0) rnr[row] = rn;
    }
    __syncthreads();

    // ---- final per-row top-2 (exact), weights + enc patch stores ----
    if (t < 32) {
        double rn = rnr[t];
        double d0 = 1e300, d1 = 1e300; int b0 = 1 << 30, b1 = 1 << 30;
        #pragma unroll
        for (int q = 0; q < 8; ++q) {
            double d = rd[t * 8 + q];
            int    c = mIdx[t * 8 + q];
            if (d < d0 || (d == d0 && c < b0)) { d1 = d0; b1 = b0; d0 = d; b0 = c; }
            else if (d < d1 || (d == d1 && c < b1)) { d1 = d; b1 = c; }
        }
        double D0 = rn + d0;
        double D1 = rn + d1;
        double inv0 = 1.0 / D0, inv1 = 1.0 / D1;
        double nrm = sqrt(inv0 * inv0 + inv1 * inv1);
        if (nrm < 1e-12) nrm = 1e-12;
        float w0 = (float)(inv0 / nrm);
        float w1 = (float)(inv1 / nrm);
        s0[t] = b0; s1[t] = b1; sw0[t] = w0; sw1[t] = w1;
        atomicAdd(&enc_sum[b0], w0);
        atomicAdd(&enc_sum[b1], w1);
        // patch the two weights into the pre-zeroed encodings row.
        // zeros for this row were issued at loop iter t and drained by the
        // issuing waves' subsequent __syncthreads (multiple barriers ago).
        enc[(size_t)(r0 + t) * KCODES + b0] = w0;
        enc[(size_t)(r0 + t) * KCODES + b1] = w1;
    }
    __syncthreads();

    // ---- quantize + loss (from xs) + NCHW write, 2 chunks of 128 channels ----
    double ls = 0.0;
    #pragma unroll
    for (int p2 = 0; p2 < 2; ++p2) {
        const int   cA = s0[row], cB = s1[row];
        const float w0 = sw0[row], w1 = sw1[row];
        const float* W0 = Wm + (size_t)cA * 256 + p2 * 128 + q8 * 16;
        const float* W1 = Wm + (size_t)cB * 256 + p2 * 128 + q8 * 16;
        #pragma unroll
        for (int v4 = 0; v4 < 4; ++v4) {
            const float4 a  = *(const float4*)(W0 + v4 * 4);
            const float4 bv = *(const float4*)(W1 + v4 * 4);
            f32x4 qv;
            qv.x = w0 * a.x + w1 * bv.x;
            qv.y = w0 * a.y + w1 * bv.y;
            qv.z = w0 * a.z + w1 * bv.z;
            qv.w = w0 * a.w + w1 * bv.w;
            float e0 = qv.x - xs[p2 * 16 + v4 * 4 + 0];
            float e1 = qv.y - xs[p2 * 16 + v4 * 4 + 1];
            float e2 = qv.z - xs[p2 * 16 + v4 * 4 + 2];
            float e3 = qv.w - xs[p2 * 16 + v4 * 4 + 3];
            ls += (double)(e0*e0 + e1*e1 + e2*e2 + e3*e3);
            const int dl = q8 * 16 + v4 * 4;
            *(f32x4*)(qtile + row * 132 + dl) = qv;
        }
        __syncthreads();
        #pragma unroll
        for (int p = 0; p < 4; ++p) {
            const int task = p * 256 + t;
            const int cl   = task >> 3;       // channel-local 0..127
            const int hwq  = task & 7;
            f32x4 v;
            v.x = qtile[(hwq * 4 + 0) * 132 + cl];
            v.y = qtile[(hwq * 4 + 1) * 132 + cl];
            v.z = qtile[(hwq * 4 + 2) * 132 + cl];
            v.w = qtile[(hwq * 4 + 3) * 132 + cl];
            *(f32x4*)(outq + ((size_t)(b * 256 + p2 * 128 + cl)) * 1024 + hw0 + hwq * 4) = v;
        }
        __syncthreads();
    }

    // ---- block loss partial ----
    #pragma unroll
    for (int off = 32; off > 0; off >>= 1) ls += __shfl_down(ls, off);
    if (lane == 0) sredd[wave] = ls;
    __syncthreads();
    if (t == 0) {
        double s = 0.0;
        #pragma unroll
        for (int w = 0; w < 4; ++w) s += sredd[w];
        loss_part[blockIdx.x] = (float)s;
    }
}

// ---------------- finalize: loss + perplexity ----------------
__global__ __launch_bounds__(256) void finalize_k(const float* __restrict__ enc_sum,
                                                  const float* __restrict__ loss_part,
                                                  float* __restrict__ out)
{
    __shared__ double sh[256];
    const int t = threadIdx.x;
    double ls = 0.0;
    for (int i = t; i < 1024; i += 256) ls += (double)loss_part[i];
    sh[t] = ls; __syncthreads();
    for (int s = 128; s > 0; s >>= 1) { if (t < s) sh[t] += sh[t + s]; __syncthreads(); }
    double loss_sum = sh[0];
    __syncthreads();
    double ps = 0.0;
    for (int k = t; k < KCODES; k += 256) {
        double p = (double)enc_sum[k] / (double)NROWS;
        ps += p * log(p + 1e-10);
    }
    sh[t] = ps; __syncthreads();
    for (int s = 128; s > 0; s >>= 1) { if (t < s) sh[t] += sh[t + s]; __syncthreads(); }
    if (t == 0) {
        out[0]        = (float)(1.25 * loss_sum / 8388608.0);
        out[OUT_PERP] = (float)exp(-sh[0]);
    }
}

extern "C" void kernel_launch(void* const* d_in, const int* in_sizes, int n_in,
                              void* d_out, int out_size, void* d_ws, size_t ws_size,
                              hipStream_t stream)
{
    const float* x  = (const float*)d_in[0];
    const float* Wm = (const float*)d_in[1];
    float* out = (float*)d_out;
    float* ws  = (float*)d_ws;

    unsigned short* Wb      = (unsigned short*)(ws + OFF_WB);
    float*          wnorm   = ws + OFF_WNORM;
    float*          enc_sum = ws + OFF_ENCSUM;
    float*          loss_p  = ws + OFF_LOSSP;
    double*         wnd     = (double*)(ws + OFF_WND);

    wprep<<<KCODES / 4, 256, 0, stream>>>(Wm, Wb, wnorm, wnd, enc_sum);
    gemm_topk_quant<<<NROWS / 32, 256, 0, stream>>>(x, Wb, wnorm, wnd, Wm, enc_sum,
                                                    out + OUT_ENC, out + OUT_Q, loss_p);
    finalize_k<<<1, 256, 0, stream>>>(enc_sum, loss_p, out);
}

// Round 9
// 241.193 us; speedup vs baseline: 1.0824x; 1.0518x over previous
//
#include <hip/hip_runtime.h>
#include <math.h>

// Problem constants (fixed by setup_inputs)
#define NROWS 32768   // 32 * 32 * 32
#define DIMS  256
#define KCODES 1024

typedef __attribute__((ext_vector_type(8))) short short8;   // 8 bf16 = 4 VGPRs
typedef __attribute__((ext_vector_type(4))) float f32x4;    // MFMA C/D & stores

// ws layout (float offsets)
static const size_t OFF_WB     = 8388608;                // [1024][256] bf16, MFMA-fragment tile order
static const size_t OFF_WNORM  = OFF_WB + 131072;        // [1024] f32
static const size_t OFF_ENCSUM = OFF_WNORM + 1024;       // [1024]
static const size_t OFF_LOSSP  = OFF_ENCSUM + 1024;      // [1024 used]
static const size_t OFF_WND    = OFF_LOSSP + 8192;       // [1024] f64 (2048 floats), 8B aligned

// out layout (float offsets): loss | quantized NCHW | perplexity | encodings
static const size_t OUT_Q    = 1;
static const size_t OUT_PERP = 8388609;
static const size_t OUT_ENC  = 8388610;

__device__ inline unsigned short f2bf(float f) {
    unsigned int u = __float_as_uint(f);
    unsigned int r = u + 0x7FFFu + ((u >> 16) & 1u);   // RNE
    return (unsigned short)(r >> 16);
}

// pack distance (fp32, low 10 mantissa bits cleared) with 10-bit code index.
__device__ inline float packdi(float d, int code) {
    return __uint_as_float((__float_as_uint(d) & 0xFFFFFC00u) | (unsigned)code);
}

// async global->LDS copy, 16B per lane (wave-uniform LDS base + lane*16)
__device__ __forceinline__ void gl_lds16(const void* gsrc, void* ldst) {
    typedef const __attribute__((address_space(1))) unsigned int GU;
    typedef __attribute__((address_space(3))) unsigned int LU;
    __builtin_amdgcn_global_load_lds((GU*)gsrc, (LU*)ldst, 16, 0, 0);
}

// ---------------- W prep: bf16 fragment-order layout + wnorm (f32+f64) ----
__global__ __launch_bounds__(256) void wprep(const float* __restrict__ Wm,
                                             unsigned short* __restrict__ Wb,
                                             float* __restrict__ wnorm,
                                             double* __restrict__ wnormd,
                                             float* __restrict__ enc_sum)
{
    const int r = blockIdx.x * 4 + (threadIdx.x >> 6);
    const int lane = threadIdx.x & 63;
    float4 v = ((const float4*)(Wm + (size_t)r * 256))[lane];
    ushort4 o;
    o.x = f2bf(v.x); o.y = f2bf(v.y); o.z = f2bf(v.z); o.w = f2bf(v.w);
    const int d0 = lane * 4;
    const int kk = d0 >> 5, quad = (d0 >> 3) & 3, jb = d0 & 7;
    const int tt = r >> 4, col = r & 15;
    const size_t idx = (size_t)tt * 4096 + (size_t)((kk * 4 + quad) * 16 + col) * 8 + jb;
    *(ushort4*)(Wb + idx) = o;
    double s = (double)v.x*(double)v.x + (double)v.y*(double)v.y
             + (double)v.z*(double)v.z + (double)v.w*(double)v.w;
    #pragma unroll
    for (int off = 32; off > 0; off >>= 1) s += __shfl_down(s, off);
    if (lane == 0) { wnormd[r] = s; wnorm[r] = (float)s; }
    if (blockIdx.x == 0) {
        #pragma unroll
        for (int q = 0; q < 4; ++q) enc_sum[threadIdx.x * 4 + q] = 0.0f;
    }
}

// ---------------- fused MFMA GEMM + top-k + fp64 refine + enc + quantize + loss ----
// 256 thr = 4 waves, 32 rows/block, grid 1024, LDS 36 KB -> 4 blocks/CU.
// Mappings:
//   MFMA:   wave w: g=w&1 (16-row group), h=w>>1 (512-code half); lane: col,quad
//   refine: row = t>>3 (0..31), q8 = t&7.
// DIM-SLICE MAP (coalescing fix): thread (row,q8) owns dims c*32 + q8*4 + k
// (c=0..7, k=0..3), xs[c*4+k]. The 8 lanes of a row thus read CONTIGUOUS
// 128B per float4 instruction in refine/quantize (vs 64B-strided 16B chunks).
// Main loop (32 iters): dbuf 2x16KB via global_load_lds; split 4+4 MFMA
// chains; med3 exact top-3 insert; in-loop enc row zero-streaming.
__global__ __launch_bounds__(256, 4) void gemm_topk_quant(
    const float* __restrict__ x, const unsigned short* __restrict__ Wb,
    const float* __restrict__ wnorm, const double* __restrict__ wnd,
    const float* __restrict__ Wm,
    float* __restrict__ enc_sum,
    float* __restrict__ enc,
    float* __restrict__ outq, float* __restrict__ loss_part)
{
    __shared__ __align__(16) char lds[36864];
    // loop: buf0 = lds[0,16K), buf1 = lds[16K,32K); wnLds @ 32K (4 KB)
    // post-loop aliases (phases separated by barriers):
    float*  sCd   = (float*)lds;                 // [96][34] f32 = 13056 B (dump->merge)
    int*    mIdx  = (int*)(lds + 13312);         // [256] -> 14336
    double* rd    = (double*)(lds + 14336);      // [256] f64 -> 16384
    float*  qtile = (float*)lds;                 // [32][132] f32 = 16896 B (epilogue)
    // small arrays live in the (post-loop dead) wnLds region:
    double* rnr   = (double*)(lds + 33792);      // [32] f64 -> 34048
    int*    s0    = (int*)(lds + 34048);         // [32] -> 34176
    int*    s1    = (int*)(lds + 34176);         // [32] -> 34304
    float*  sw0   = (float*)(lds + 34304);       // [32] -> 34432
    float*  sw1   = (float*)(lds + 34432);       // [32] -> 34560
    double* sredd = (double*)(lds + 34560);      // [4]  -> 34592
    unsigned short* xtile = (unsigned short*)(lds + 16384);  // [32][256] bf16 swizzled, pre-loop
    float*  wnLds = (float*)(lds + 32768);       // [1024] f32 (loop only)

    const int t    = threadIdx.x;
    const int wave = t >> 6;
    const int g    = wave & 1;
    const int h    = wave >> 1;
    const int lane = t & 63;
    const int col  = lane & 15;
    const int quad = lane >> 4;
    const int r0   = blockIdx.x * 32;
    const int b    = r0 >> 10;
    const int hw0  = r0 & 1023;
    const float* xblk = x + (size_t)b * 262144 + hw0;   // + d*1024 + hw_local

    const int row = t >> 3;   // refine/epilogue row (hw local), 0..31
    const int q8  = t & 7;    // dim-slice

    // ---- issue prologue B staging (cc=0 -> buf0) + wnorm -> wnLds first ----
    const char* wb_bytes = (const char*)Wb;
    {
        const char* src = wb_bytes + (size_t)(h * 32) * 8192 + g * 4096;
        char* dstl = lds + h * 8192 + g * 4096;
        #pragma unroll
        for (int q = 0; q < 4; ++q)
            gl_lds16(src + q * 1024 + lane * 16, dstl + q * 1024);
        gl_lds16((const char*)wnorm + wave * 1024 + lane * 16,
                 (char*)wnLds + wave * 1024);
    }

    // ---- xs: this thread's 32 x values, dims c*32 + q8*4 + k ----
    float xs[32];
    {
        const float* xr = xblk + row;
        #pragma unroll
        for (int c = 0; c < 8; ++c)
            #pragma unroll
            for (int k = 0; k < 4; ++k)
                xs[c * 4 + k] = xr[(size_t)(c * 32 + q8 * 4 + k) * 1024];
    }

    // ---- build bf16 x-tile [32][256] in LDS (buf1 alias) from xs ----
    // XOR-swizzle short-index bits 3..5 with row&7 to spread banks.
    #pragma unroll
    for (int c = 0; c < 8; ++c) {
        ushort4 o;
        o.x = f2bf(xs[c * 4 + 0]);
        o.y = f2bf(xs[c * 4 + 1]);
        o.z = f2bf(xs[c * 4 + 2]);
        o.w = f2bf(xs[c * 4 + 3]);
        const int xi = (row * 256 + c * 32 + q8 * 4) ^ ((row & 7) << 3);
        *(ushort4*)(xtile + xi) = o;
    }
    __syncthreads();

    // ---- A fragments from x-tile (rows g*16..g*16+15) ----
    short8 af[8];
    #pragma unroll
    for (int kk = 0; kk < 8; ++kk) {
        const int xi = ((g * 16 + col) * 256 + kk * 32 + quad * 8) ^ ((col & 7) << 3);
        af[kk] = *(const short8*)(xtile + xi);
    }
    __syncthreads();   // af reads done; buf0+wnLds staged. cc=0 may overwrite xtile.

    float m0[4], m1[4], m2[4];
    #pragma unroll
    for (int r = 0; r < 4; ++r) { m0[r] = 3.4e38f; m1[r] = 3.4e38f; m2[r] = 3.4e38f; }

    const f32x4 zero4 = {0.f, 0.f, 0.f, 0.f};
    for (int cc = 0; cc < 32; ++cc) {
        if (cc < 31) {
            const char* src = wb_bytes + (size_t)(h * 32 + cc + 1) * 8192 + g * 4096;
            char* dstl = lds + ((cc + 1) & 1) * 16384 + h * 8192 + g * 4096;
            #pragma unroll
            for (int q = 0; q < 4; ++q)
                gl_lds16(src + q * 1024 + lane * 16, dstl + q * 1024);
        }
        // zero-stream one encodings row per iteration (coalesced 4 KB)
        *(f32x4*)(enc + (size_t)(r0 + cc) * KCODES + t * 4) = zero4;

        const char* bb = lds + (cc & 1) * 16384 + h * 8192;
        f32x4 acc_a = {0.f, 0.f, 0.f, 0.f};
        f32x4 acc_b = {0.f, 0.f, 0.f, 0.f};
        #pragma unroll
        for (int kk = 0; kk < 4; ++kk) {
            short8 b0 = *(const short8*)(bb + kk * 1024 + lane * 16);
            short8 b1 = *(const short8*)(bb + (kk + 4) * 1024 + lane * 16);
            acc_a = __builtin_amdgcn_mfma_f32_16x16x32_bf16(af[kk], b0, acc_a, 0, 0, 0);
            acc_b = __builtin_amdgcn_mfma_f32_16x16x32_bf16(af[kk + 4], b1, acc_b, 0, 0, 0);
        }
        const int code0 = h * 512 + cc * 16 + col;
        const float wn0 = wnLds[code0];
        #pragma unroll
        for (int r = 0; r < 4; ++r) {
            float pv0 = packdi(fmaf(-2.0f, acc_a[r] + acc_b[r], wn0), code0);
            // exact sorted-3 insert via med3 (3 ops)
            m2[r] = __builtin_amdgcn_fmed3f(m1[r], m2[r], pv0);
            m1[r] = __builtin_amdgcn_fmed3f(m0[r], m1[r], pv0);
            m0[r] = fminf(m0[r], pv0);
        }
        __syncthreads();   // staged data for cc+1 visible; buf[cc&1] reads done
    }

    // ---- dump per-lane candidates, transposed layout [96 slots][34 rows] ----
    #pragma unroll
    for (int r = 0; r < 4; ++r) {
        const int rl = g * 16 + quad * 4 + r;
        const int s  = h * 48 + col * 3;
        sCd[(s + 0) * 34 + rl] = m0[r];
        sCd[(s + 1) * 34 + rl] = m1[r];
        sCd[(s + 2) * 34 + rl] = m2[r];
    }
    __syncthreads();

    // ---- parallel exact top-8 merge: 8 threads/row, 12 slots each ----
    {
        float a0 = 3.4e38f, a1 = 3.4e38f, a2 = 3.4e38f, a3 = 3.4e38f,
              a4 = 3.4e38f, a5 = 3.4e38f, a6 = 3.4e38f, a7 = 3.4e38f;
        #pragma unroll
        for (int i = 0; i < 12; ++i) {
            float d = sCd[(q8 * 12 + i) * 34 + row];
            if (d < a7) {
                a7 = d; float tf;
                if (a7 < a6) { tf = a7; a7 = a6; a6 = tf; }
                if (a6 < a5) { tf = a6; a6 = a5; a5 = tf; }
                if (a5 < a4) { tf = a5; a5 = a4; a4 = tf; }
                if (a4 < a3) { tf = a4; a4 = a3; a3 = tf; }
                if (a3 < a2) { tf = a3; a3 = a2; a2 = tf; }
                if (a2 < a1) { tf = a2; a2 = a1; a1 = tf; }
                if (a1 < a0) { tf = a1; a1 = a0; a0 = tf; }
            }
        }
        // 8 rounds: global min of the 8 heads (values unique via packed code bits)
        float sel = 3.4e38f;
        #pragma unroll
        for (int q = 0; q < 8; ++q) {
            float m = a0;
            m = fminf(m, __shfl_xor(m, 1));
            m = fminf(m, __shfl_xor(m, 2));
            m = fminf(m, __shfl_xor(m, 4));
            if (q8 == q) sel = m;
            if (a0 == m) { a0 = a1; a1 = a2; a2 = a3; a3 = a4;
                           a4 = a5; a5 = a6; a6 = a7; a7 = 3.4e38f; }
        }
        mIdx[row * 8 + q8] = (int)(__float_as_uint(sel) & 1023u);
    }
    __syncthreads();

    // ---- fp64 refine from xs regs: coalesced 128B W reads per row-octet ----
    {
        int cd[8];
        #pragma unroll
        for (int c8 = 0; c8 < 8; ++c8) cd[c8] = mIdx[row * 8 + c8];
        double dot[8];
        #pragma unroll
        for (int c8 = 0; c8 < 8; ++c8) dot[c8] = 0.0;
        double rn = 0.0;
        #pragma unroll
        for (int c = 0; c < 8; ++c) {
            const int d0 = c * 32 + q8 * 4;
            const double x0 = (double)xs[c * 4 + 0];
            const double x1 = (double)xs[c * 4 + 1];
            const double x2 = (double)xs[c * 4 + 2];
            const double x3 = (double)xs[c * 4 + 3];
            rn += x0*x0 + x1*x1 + x2*x2 + x3*x3;
            #pragma unroll
            for (int c8 = 0; c8 < 8; ++c8) {
                const float4 wv = *(const float4*)(Wm + (size_t)cd[c8] * 256 + d0);
                dot[c8] += x0 * (double)wv.x + x1 * (double)wv.y
                         + x2 * (double)wv.z + x3 * (double)wv.w;
            }
        }
        #pragma unroll
        for (int m = 1; m < 8; m <<= 1) {
            #pragma unroll
            for (int c8 = 0; c8 < 8; ++c8) dot[c8] += __shfl_xor(dot[c8], m);
            rn += __shfl_xor(rn, m);
        }
        // static select of this thread's candidate (avoid dynamic reg indexing)
        int myc = 0; double mydot = 0.0;
        #pragma unroll
        for (int c8 = 0; c8 < 8; ++c8)
            if (q8 == c8) { myc = cd[c8]; mydot = dot[c8]; }
        rd[row * 8 + q8] = wnd[myc] - 2.0 * mydot;
        if (q8 == 0) rnr[row] = rn;
    }
    __syncthreads();

    // ---- final per-row top-2 (exact), weights + enc patch stores ----
    if (t < 32) {
        double rn = rnr[t];
        double d0 = 1e300, d1 = 1e300; int b0 = 1 << 30, b1 = 1 << 30;
        #pragma unroll
        for (int q = 0; q < 8; ++q) {
            double d = rd[t * 8 + q];
            int    c = mIdx[t * 8 + q];
            if (d < d0 || (d == d0 && c < b0)) { d1 = d0; b1 = b0; d0 = d; b0 = c; }
            else if (d < d1 || (d == d1 && c < b1)) { d1 = d; b1 = c; }
        }
        double D0 = rn + d0;
        double D1 = rn + d1;
        double inv0 = 1.0 / D0, inv1 = 1.0 / D1;
        double nrm = sqrt(inv0 * inv0 + inv1 * inv1);
        if (nrm < 1e-12) nrm = 1e-12;
        float w0 = (float)(inv0 / nrm);
        float w1 = (float)(inv1 / nrm);
        s0[t] = b0; s1[t] = b1; sw0[t] = w0; sw1[t] = w1;
        atomicAdd(&enc_sum[b0], w0);
        atomicAdd(&enc_sum[b1], w1);
        // patch the two weights into the pre-zeroed encodings row.
        // zeros for this row were issued at loop iter t and drained by the
        // issuing waves' subsequent __syncthreads (multiple barriers ago).
        enc[(size_t)(r0 + t) * KCODES + b0] = w0;
        enc[(size_t)(r0 + t) * KCODES + b1] = w1;
    }
    __syncthreads();

    // ---- quantize + loss (from xs) + NCHW write, 2 chunks of 128 channels ----
    double ls = 0.0;
    #pragma unroll
    for (int p2 = 0; p2 < 2; ++p2) {
        const int   cA = s0[row], cB = s1[row];
        const float w0 = sw0[row], w1 = sw1[row];
        #pragma unroll
        for (int cq = 0; cq < 4; ++cq) {
            const int c  = p2 * 4 + cq;            // global chunk
            const int dg = c * 32 + q8 * 4;        // global dim
            const float4 a  = *(const float4*)(Wm + (size_t)cA * 256 + dg);
            const float4 bv = *(const float4*)(Wm + (size_t)cB * 256 + dg);
            f32x4 qv;
            qv.x = w0 * a.x + w1 * bv.x;
            qv.y = w0 * a.y + w1 * bv.y;
            qv.z = w0 * a.z + w1 * bv.z;
            qv.w = w0 * a.w + w1 * bv.w;
            float e0 = qv.x - xs[c * 4 + 0];
            float e1 = qv.y - xs[c * 4 + 1];
            float e2 = qv.z - xs[c * 4 + 2];
            float e3 = qv.w - xs[c * 4 + 3];
            ls += (double)(e0*e0 + e1*e1 + e2*e2 + e3*e3);
            const int dl = cq * 32 + q8 * 4;       // within-half dim
            *(f32x4*)(qtile + row * 132 + dl) = qv;
        }
        __syncthreads();
        #pragma unroll
        for (int p = 0; p < 4; ++p) {
            const int task = p * 256 + t;
            const int cl   = task >> 3;       // channel-local 0..127
            const int hwq  = task & 7;
            f32x4 v;
            v.x = qtile[(hwq * 4 + 0) * 132 + cl];
            v.y = qtile[(hwq * 4 + 1) * 132 + cl];
            v.z = qtile[(hwq * 4 + 2) * 132 + cl];
            v.w = qtile[(hwq * 4 + 3) * 132 + cl];
            *(f32x4*)(outq + ((size_t)(b * 256 + p2 * 128 + cl)) * 1024 + hw0 + hwq * 4) = v;
        }
        __syncthreads();
    }

    // ---- block loss partial ----
    #pragma unroll
    for (int off = 32; off > 0; off >>= 1) ls += __shfl_down(ls, off);
    if (lane == 0) sredd[wave] = ls;
    __syncthreads();
    if (t == 0) {
        double s = 0.0;
        #pragma unroll
        for (int w = 0; w < 4; ++w) s += sredd[w];
        loss_part[blockIdx.x] = (float)s;
    }
}

// ---------------- finalize: loss + perplexity ----------------
__global__ __launch_bounds__(256) void finalize_k(const float* __restrict__ enc_sum,
                                                  const float* __restrict__ loss_part,
                                                  float* __restrict__ out)
{
    __shared__ double sh[256];
    const int t = threadIdx.x;
    double ls = 0.0;
    for (int i = t; i < 1024; i += 256) ls += (double)loss_part[i];
    sh[t] = ls; __syncthreads();
    for (int s = 128; s > 0; s >>= 1) { if (t < s) sh[t] += sh[t + s]; __syncthreads(); }
    double loss_sum = sh[0];
    __syncthreads();
    double ps = 0.0;
    for (int k = t; k < KCODES; k += 256) {
        double p = (double)enc_sum[k] / (double)NROWS;
        ps += p * log(p + 1e-10);
    }
    sh[t] = ps; __syncthreads();
    for (int s = 128; s > 0; s >>= 1) { if (t < s) sh[t] += sh[t + s]; __syncthreads(); }
    if (t == 0) {
        out[0]        = (float)(1.25 * loss_sum / 8388608.0);
        out[OUT_PERP] = (float)exp(-sh[0]);
    }
}

extern "C" void kernel_launch(void* const* d_in, const int* in_sizes, int n_in,
                              void* d_out, int out_size, void* d_ws, size_t ws_size,
                              hipStream_t stream)
{
    const float* x  = (const float*)d_in[0];
    const float* Wm = (const float*)d_in[1];
    float* out = (float*)d_out;
    float* ws  = (float*)d_ws;

    unsigned short* Wb      = (unsigned short*)(ws + OFF_WB);
    float*          wnorm   = ws + OFF_WNORM;
    float*          enc_sum = ws + OFF_ENCSUM;
    float*          loss_p  = ws + OFF_LOSSP;
    double*         wnd     = (double*)(ws + OFF_WND);

    wprep<<<KCODES / 4, 256, 0, stream>>>(Wm, Wb, wnorm, wnd, enc_sum);
    gemm_topk_quant<<<NROWS / 32, 256, 0, stream>>>(x, Wb, wnorm, wnd, Wm, enc_sum,
                                                    out + OUT_ENC, out + OUT_Q, loss_p);
    finalize_k<<<1, 256, 0, stream>>>(enc_sum, loss_p, out);
}

// Round 10
// 238.069 us; speedup vs baseline: 1.0966x; 1.0131x over previous
//
#include <hip/hip_runtime.h>
#include <math.h>

// Problem constants (fixed by setup_inputs)
#define NROWS 32768   // 32 * 32 * 32
#define DIMS  256
#define KCODES 1024

typedef __attribute__((ext_vector_type(8))) short short8;   // 8 bf16 = 4 VGPRs
typedef __attribute__((ext_vector_type(4))) float f32x4;    // MFMA C/D & stores

// ws layout (float offsets)
static const size_t OFF_WB     = 8388608;                // [1024][256] bf16, MFMA-fragment tile order
static const size_t OFF_WNORM  = OFF_WB + 131072;        // [1024] f32
static const size_t OFF_ENCSUM = OFF_WNORM + 1024;       // [1024]
static const size_t OFF_LOSSP  = OFF_ENCSUM + 1024;      // [1024 used]
static const size_t OFF_WND    = OFF_LOSSP + 8192;       // [1024] f64 (2048 floats), 8B aligned

// out layout (float offsets): loss | quantized NCHW | perplexity | encodings
static const size_t OUT_Q    = 1;
static const size_t OUT_PERP = 8388609;
static const size_t OUT_ENC  = 8388610;

__device__ inline unsigned short f2bf(float f) {
    unsigned int u = __float_as_uint(f);
    unsigned int r = u + 0x7FFFu + ((u >> 16) & 1u);   // RNE
    return (unsigned short)(r >> 16);
}

// pack distance (fp32, low 10 mantissa bits cleared) with 10-bit code index.
__device__ inline float packdi(float d, int code) {
    return __uint_as_float((__float_as_uint(d) & 0xFFFFFC00u) | (unsigned)code);
}

// async global->LDS copy, 16B per lane (wave-uniform LDS base + lane*16)
__device__ __forceinline__ void gl_lds16(const void* gsrc, void* ldst) {
    typedef const __attribute__((address_space(1))) unsigned int GU;
    typedef __attribute__((address_space(3))) unsigned int LU;
    __builtin_amdgcn_global_load_lds((GU*)gsrc, (LU*)ldst, 16, 0, 0);
}

// ---------------- W prep: bf16 fragment-order layout + wnorm (f32+f64) ----
__global__ __launch_bounds__(256) void wprep(const float* __restrict__ Wm,
                                             unsigned short* __restrict__ Wb,
                                             float* __restrict__ wnorm,
                                             double* __restrict__ wnormd,
                                             float* __restrict__ enc_sum)
{
    const int r = blockIdx.x * 4 + (threadIdx.x >> 6);
    const int lane = threadIdx.x & 63;
    float4 v = ((const float4*)(Wm + (size_t)r * 256))[lane];
    ushort4 o;
    o.x = f2bf(v.x); o.y = f2bf(v.y); o.z = f2bf(v.z); o.w = f2bf(v.w);
    const int d0 = lane * 4;
    const int kk = d0 >> 5, quad = (d0 >> 3) & 3, jb = d0 & 7;
    const int tt = r >> 4, col = r & 15;
    const size_t idx = (size_t)tt * 4096 + (size_t)((kk * 4 + quad) * 16 + col) * 8 + jb;
    *(ushort4*)(Wb + idx) = o;
    double s = (double)v.x*(double)v.x + (double)v.y*(double)v.y
             + (double)v.z*(double)v.z + (double)v.w*(double)v.w;
    #pragma unroll
    for (int off = 32; off > 0; off >>= 1) s += __shfl_down(s, off);
    if (lane == 0) { wnormd[r] = s; wnorm[r] = (float)s; }
    if (blockIdx.x == 0) {
        #pragma unroll
        for (int q = 0; q < 4; ++q) enc_sum[threadIdx.x * 4 + q] = 0.0f;
    }
}

// ---------------- fused MFMA GEMM + top-k + fp64 refine + enc + quantize + loss ----
// 256 thr = 4 waves, 32 rows/block, grid 1024, LDS 36 KB -> 4 blocks/CU.
// Mappings:
//   MFMA:   wave w: g=w&1 (16-row group), h=w>>1 (512-code half); lane: col,quad
//   refine: row = t>>3 (0..31), q8 = t&7; thread owns dims c*32 + q8*4 + k.
// x INGESTION (R10): two-pass f32 LDS bounce — coalesced float4 global reads
// of the [32 hw][128 d] half-tile into a row-XOR-swizzled LDS buffer; xs and
// af both extracted from LDS (b128, floor-conflict). Kills 32 scattered
// scalar loads/thread and the separate bf16-xtile phase.
// Main loop (32 iters): dbuf 2x16KB via global_load_lds; split 4+4 MFMA
// chains; med3 exact top-3 insert; in-loop enc row zero-streaming.
// Quantize (R10): single pass through full-width qtile[32][264].
__global__ __launch_bounds__(256, 4) void gemm_topk_quant(
    const float* __restrict__ x, const unsigned short* __restrict__ Wb,
    const float* __restrict__ wnorm, const double* __restrict__ wnd,
    const float* __restrict__ Wm,
    float* __restrict__ enc_sum,
    float* __restrict__ enc,
    float* __restrict__ outq, float* __restrict__ loss_part)
{
    __shared__ __align__(16) char lds[36864];
    // loop: buf0 = lds[0,16K), buf1 = lds[16K,32K); wnLds @ 32K (4 KB)
    // post-loop aliases (phases separated by barriers):
    float*  sCd   = (float*)lds;                 // [96][34] f32 = 13056 B (dump->merge)
    int*    mIdx  = (int*)(lds + 13312);         // [256] -> 14336
    double* rd    = (double*)(lds + 14336);      // [256] f64 -> 16384
    float*  qtile = (float*)lds;                 // [32][264] f32 = 33792 B (epilogue)
    // small arrays live past qtile (wnLds region, dead post-loop):
    double* rnr   = (double*)(lds + 33792);      // [32] f64 -> 34048
    int*    s0    = (int*)(lds + 34048);         // [32] -> 34176
    int*    s1    = (int*)(lds + 34176);         // [32] -> 34304
    float*  sw0   = (float*)(lds + 34304);       // [32] -> 34432
    float*  sw1   = (float*)(lds + 34432);       // [32] -> 34560
    double* sredd = (double*)(lds + 34560);      // [4]  -> 34592
    float*  xbounce = (float*)(lds + 16384);     // [32][128] f32 swizzled, pre-loop (buf1)
    float*  wnLds = (float*)(lds + 32768);       // [1024] f32 (loop only)

    const int t    = threadIdx.x;
    const int wave = t >> 6;
    const int g    = wave & 1;
    const int h    = wave >> 1;
    const int lane = t & 63;
    const int col  = lane & 15;
    const int quad = lane >> 4;
    const int r0   = blockIdx.x * 32;
    const int b    = r0 >> 10;
    const int hw0  = r0 & 1023;
    const float* xblk = x + (size_t)b * 262144 + hw0;   // + d*1024 + hw_local

    const int row = t >> 3;   // refine/epilogue row (hw local), 0..31
    const int q8  = t & 7;    // dim-slice

    // ---- issue prologue B staging (cc=0 -> buf0) + wnorm -> wnLds first ----
    const char* wb_bytes = (const char*)Wb;
    {
        const char* src = wb_bytes + (size_t)(h * 32) * 8192 + g * 4096;
        char* dstl = lds + h * 8192 + g * 4096;
        #pragma unroll
        for (int q = 0; q < 4; ++q)
            gl_lds16(src + q * 1024 + lane * 16, dstl + q * 1024);
        gl_lds16((const char*)wnorm + wave * 1024 + lane * 16,
                 (char*)wnLds + wave * 1024);
    }

    // ---- x ingestion: two-pass coalesced bounce through LDS ----
    float xs[32];
    short8 af[8];
    const int hwq   = t & 7;       // hw chunk (load mapping)
    const int dbase = t >> 3;      // 0..31   (load mapping)
    const int arow  = g * 16 + col;
    #pragma unroll
    for (int h2 = 0; h2 < 2; ++h2) {
        // coalesced global loads: 8 segments of 128B per wave-instr
        float4 xv0, xv1, xv2, xv3;
        {
            const float* xp = xblk + hwq * 4;
            xv0 = *(const float4*)(xp + (size_t)(h2 * 128 +  0 + dbase) * 1024);
            xv1 = *(const float4*)(xp + (size_t)(h2 * 128 + 32 + dbase) * 1024);
            xv2 = *(const float4*)(xp + (size_t)(h2 * 128 + 64 + dbase) * 1024);
            xv3 = *(const float4*)(xp + (size_t)(h2 * 128 + 96 + dbase) * 1024);
        }
        if (h2) __syncthreads();   // pass-0 readers done before overwrite
        // scatter to LDS [hw][dloc], word-XOR-swizzled by (hw&7)<<2 (16B unit)
        #pragma unroll
        for (int rr = 0; rr < 4; ++rr) {
            const float4 xv = (rr == 0) ? xv0 : (rr == 1) ? xv1 : (rr == 2) ? xv2 : xv3;
            const int dloc = rr * 32 + dbase;
            #pragma unroll
            for (int j = 0; j < 4; ++j) {
                const int hw = hwq * 4 + j;
                const float vj = (j == 0) ? xv.x : (j == 1) ? xv.y : (j == 2) ? xv.z : xv.w;
                xbounce[(hw * 128 + dloc) ^ ((hw & 7) << 2)] = vj;
            }
        }
        __syncthreads();
        // xs: 4 b128 reads (dims c*32 + q8*4 .. +3)
        #pragma unroll
        for (int c2 = 0; c2 < 4; ++c2) {
            const int w = (row * 128 + c2 * 32 + q8 * 4) ^ ((row & 7) << 2);
            f32x4 v = *(const f32x4*)(xbounce + w);
            xs[(h2 * 4 + c2) * 4 + 0] = v.x;
            xs[(h2 * 4 + c2) * 4 + 1] = v.y;
            xs[(h2 * 4 + c2) * 4 + 2] = v.z;
            xs[(h2 * 4 + c2) * 4 + 3] = v.w;
        }
        // af: direct f32 -> bf16 fragments (rows g*16..g*16+15)
        #pragma unroll
        for (int kk2 = 0; kk2 < 4; ++kk2) {
            const int dloc = kk2 * 32 + quad * 8;
            const int wA = (arow * 128 + dloc) ^ ((arow & 7) << 2);
            const int wB = (arow * 128 + dloc + 4) ^ ((arow & 7) << 2);
            f32x4 u = *(const f32x4*)(xbounce + wA);
            f32x4 v = *(const f32x4*)(xbounce + wB);
            short8 f;
            f[0] = (short)f2bf(u.x); f[1] = (short)f2bf(u.y);
            f[2] = (short)f2bf(u.z); f[3] = (short)f2bf(u.w);
            f[4] = (short)f2bf(v.x); f[5] = (short)f2bf(v.y);
            f[6] = (short)f2bf(v.z); f[7] = (short)f2bf(v.w);
            af[h2 * 4 + kk2] = f;
        }
    }
    __syncthreads();   // pass-1 reads done; buf0+wnLds staged; cc=0 may write buf1

    float m0[4], m1[4], m2[4];
    #pragma unroll
    for (int r = 0; r < 4; ++r) { m0[r] = 3.4e38f; m1[r] = 3.4e38f; m2[r] = 3.4e38f; }

    const f32x4 zero4 = {0.f, 0.f, 0.f, 0.f};
    for (int cc = 0; cc < 32; ++cc) {
        if (cc < 31) {
            const char* src = wb_bytes + (size_t)(h * 32 + cc + 1) * 8192 + g * 4096;
            char* dstl = lds + ((cc + 1) & 1) * 16384 + h * 8192 + g * 4096;
            #pragma unroll
            for (int q = 0; q < 4; ++q)
                gl_lds16(src + q * 1024 + lane * 16, dstl + q * 1024);
        }
        // zero-stream one encodings row per iteration (coalesced 4 KB)
        *(f32x4*)(enc + (size_t)(r0 + cc) * KCODES + t * 4) = zero4;

        const char* bb = lds + (cc & 1) * 16384 + h * 8192;
        f32x4 acc_a = {0.f, 0.f, 0.f, 0.f};
        f32x4 acc_b = {0.f, 0.f, 0.f, 0.f};
        #pragma unroll
        for (int kk = 0; kk < 4; ++kk) {
            short8 b0 = *(const short8*)(bb + kk * 1024 + lane * 16);
            short8 b1 = *(const short8*)(bb + (kk + 4) * 1024 + lane * 16);
            acc_a = __builtin_amdgcn_mfma_f32_16x16x32_bf16(af[kk], b0, acc_a, 0, 0, 0);
            acc_b = __builtin_amdgcn_mfma_f32_16x16x32_bf16(af[kk + 4], b1, acc_b, 0, 0, 0);
        }
        const int code0 = h * 512 + cc * 16 + col;
        const float wn0 = wnLds[code0];
        #pragma unroll
        for (int r = 0; r < 4; ++r) {
            float pv0 = packdi(fmaf(-2.0f, acc_a[r] + acc_b[r], wn0), code0);
            // exact sorted-3 insert via med3 (3 ops)
            m2[r] = __builtin_amdgcn_fmed3f(m1[r], m2[r], pv0);
            m1[r] = __builtin_amdgcn_fmed3f(m0[r], m1[r], pv0);
            m0[r] = fminf(m0[r], pv0);
        }
        __syncthreads();   // staged data for cc+1 visible; buf[cc&1] reads done
    }

    // ---- dump per-lane candidates, transposed layout [96 slots][34 rows] ----
    #pragma unroll
    for (int r = 0; r < 4; ++r) {
        const int rl = g * 16 + quad * 4 + r;
        const int s  = h * 48 + col * 3;
        sCd[(s + 0) * 34 + rl] = m0[r];
        sCd[(s + 1) * 34 + rl] = m1[r];
        sCd[(s + 2) * 34 + rl] = m2[r];
    }
    __syncthreads();

    // ---- parallel exact top-8 merge: 8 threads/row, 12 slots each ----
    {
        float a0 = 3.4e38f, a1 = 3.4e38f, a2 = 3.4e38f, a3 = 3.4e38f,
              a4 = 3.4e38f, a5 = 3.4e38f, a6 = 3.4e38f, a7 = 3.4e38f;
        #pragma unroll
        for (int i = 0; i < 12; ++i) {
            float d = sCd[(q8 * 12 + i) * 34 + row];
            if (d < a7) {
                a7 = d; float tf;
                if (a7 < a6) { tf = a7; a7 = a6; a6 = tf; }
                if (a6 < a5) { tf = a6; a6 = a5; a5 = tf; }
                if (a5 < a4) { tf = a5; a5 = a4; a4 = tf; }
                if (a4 < a3) { tf = a4; a4 = a3; a3 = tf; }
                if (a3 < a2) { tf = a3; a3 = a2; a2 = tf; }
                if (a2 < a1) { tf = a2; a2 = a1; a1 = tf; }
                if (a1 < a0) { tf = a1; a1 = a0; a0 = tf; }
            }
        }
        // 8 rounds: global min of the 8 heads (values unique via packed code bits)
        float sel = 3.4e38f;
        #pragma unroll
        for (int q = 0; q < 8; ++q) {
            float m = a0;
            m = fminf(m, __shfl_xor(m, 1));
            m = fminf(m, __shfl_xor(m, 2));
            m = fminf(m, __shfl_xor(m, 4));
            if (q8 == q) sel = m;
            if (a0 == m) { a0 = a1; a1 = a2; a2 = a3; a3 = a4;
                           a4 = a5; a5 = a6; a6 = a7; a7 = 3.4e38f; }
        }
        mIdx[row * 8 + q8] = (int)(__float_as_uint(sel) & 1023u);
    }
    __syncthreads();

    // ---- fp64 refine from xs regs: coalesced 128B W reads per row-octet ----
    {
        int cd[8];
        #pragma unroll
        for (int c8 = 0; c8 < 8; ++c8) cd[c8] = mIdx[row * 8 + c8];
        double dot[8];
        #pragma unroll
        for (int c8 = 0; c8 < 8; ++c8) dot[c8] = 0.0;
        double rn = 0.0;
        #pragma unroll
        for (int c = 0; c < 8; ++c) {
            const int d0 = c * 32 + q8 * 4;
            const double x0 = (double)xs[c * 4 + 0];
            const double x1 = (double)xs[c * 4 + 1];
            const double x2 = (double)xs[c * 4 + 2];
            const double x3 = (double)xs[c * 4 + 3];
            rn += x0*x0 + x1*x1 + x2*x2 + x3*x3;
            #pragma unroll
            for (int c8 = 0; c8 < 8; ++c8) {
                const float4 wv = *(const float4*)(Wm + (size_t)cd[c8] * 256 + d0);
                dot[c8] += x0 * (double)wv.x + x1 * (double)wv.y
                         + x2 * (double)wv.z + x3 * (double)wv.w;
            }
        }
        #pragma unroll
        for (int m = 1; m < 8; m <<= 1) {
            #pragma unroll
            for (int c8 = 0; c8 < 8; ++c8) dot[c8] += __shfl_xor(dot[c8], m);
            rn += __shfl_xor(rn, m);
        }
        // static select of this thread's candidate (avoid dynamic reg indexing)
        int myc = 0; double mydot = 0.0;
        #pragma unroll
        for (int c8 = 0; c8 < 8; ++c8)
            if (q8 == c8) { myc = cd[c8]; mydot = dot[c8]; }
        rd[row * 8 + q8] = wnd[myc] - 2.0 * mydot;
        if (q8 == 0) rnr[row] = rn;
    }
    __syncthreads();

    // ---- final per-row top-2 (exact), weights + enc patch stores ----
    if (t < 32) {
        double rn = rnr[t];
        double d0 = 1e300, d1 = 1e300; int b0 = 1 << 30, b1 = 1 << 30;
        #pragma unroll
        for (int q = 0; q < 8; ++q) {
            double d = rd[t * 8 + q];
            int    c = mIdx[t * 8 + q];
            if (d < d0 || (d == d0 && c < b0)) { d1 = d0; b1 = b0; d0 = d; b0 = c; }
            else if (d < d1 || (d == d1 && c < b1)) { d1 = d; b1 = c; }
        }
        double D0 = rn + d0;
        double D1 = rn + d1;
        double inv0 = 1.0 / D0, inv1 = 1.0 / D1;
        double nrm = sqrt(inv0 * inv0 + inv1 * inv1);
        if (nrm < 1e-12) nrm = 1e-12;
        float w0 = (float)(inv0 / nrm);
        float w1 = (float)(inv1 / nrm);
        s0[t] = b0; s1[t] = b1; sw0[t] = w0; sw1[t] = w1;
        atomicAdd(&enc_sum[b0], w0);
        atomicAdd(&enc_sum[b1], w1);
        // patch the two weights into the pre-zeroed encodings row.
        enc[(size_t)(r0 + t) * KCODES + b0] = w0;
        enc[(size_t)(r0 + t) * KCODES + b1] = w1;
    }
    __syncthreads();

    // ---- quantize + loss (from xs) + NCHW write, single full-width pass ----
    double ls = 0.0;
    {
        const int   cA = s0[row], cB = s1[row];
        const float w0 = sw0[row], w1 = sw1[row];
        #pragma unroll
        for (int c = 0; c < 8; ++c) {
            const int dg = c * 32 + q8 * 4;
            const float4 a  = *(const float4*)(Wm + (size_t)cA * 256 + dg);
            const float4 bv = *(const float4*)(Wm + (size_t)cB * 256 + dg);
            f32x4 qv;
            qv.x = w0 * a.x + w1 * bv.x;
            qv.y = w0 * a.y + w1 * bv.y;
            qv.z = w0 * a.z + w1 * bv.z;
            qv.w = w0 * a.w + w1 * bv.w;
            float e0 = qv.x - xs[c * 4 + 0];
            float e1 = qv.y - xs[c * 4 + 1];
            float e2 = qv.z - xs[c * 4 + 2];
            float e3 = qv.w - xs[c * 4 + 3];
            ls += (double)(e0*e0 + e1*e1 + e2*e2 + e3*e3);
            *(f32x4*)(qtile + row * 264 + dg) = qv;
        }
    }
    __syncthreads();
    #pragma unroll
    for (int p = 0; p < 8; ++p) {
        const int task = p * 256 + t;
        const int cl   = task >> 3;       // channel 0..255
        const int hq   = task & 7;
        f32x4 v;
        v.x = qtile[(hq * 4 + 0) * 264 + cl];
        v.y = qtile[(hq * 4 + 1) * 264 + cl];
        v.z = qtile[(hq * 4 + 2) * 264 + cl];
        v.w = qtile[(hq * 4 + 3) * 264 + cl];
        *(f32x4*)(outq + ((size_t)(b * 256 + cl)) * 1024 + hw0 + hq * 4) = v;
    }

    // ---- block loss partial ----
    #pragma unroll
    for (int off = 32; off > 0; off >>= 1) ls += __shfl_down(ls, off);
    if (lane == 0) sredd[wave] = ls;
    __syncthreads();
    if (t == 0) {
        double s = 0.0;
        #pragma unroll
        for (int w = 0; w < 4; ++w) s += sredd[w];
        loss_part[blockIdx.x] = (float)s;
    }
}

// ---------------- finalize: loss + perplexity ----------------
__global__ __launch_bounds__(256) void finalize_k(const float* __restrict__ enc_sum,
                                                  const float* __restrict__ loss_part,
                                                  float* __restrict__ out)
{
    __shared__ double sh[256];
    const int t = threadIdx.x;
    double ls = 0.0;
    for (int i = t; i < 1024; i += 256) ls += (double)loss_part[i];
    sh[t] = ls; __syncthreads();
    for (int s = 128; s > 0; s >>= 1) { if (t < s) sh[t] += sh[t + s]; __syncthreads(); }
    double loss_sum = sh[0];
    __syncthreads();
    double ps = 0.0;
    for (int k = t; k < KCODES; k += 256) {
        double p = (double)enc_sum[k] / (double)NROWS;
        ps += p * log(p + 1e-10);
    }
    sh[t] = ps; __syncthreads();
    for (int s = 128; s > 0; s >>= 1) { if (t < s) sh[t] += sh[t + s]; __syncthreads(); }
    if (t == 0) {
        out[0]        = (float)(1.25 * loss_sum / 8388608.0);
        out[OUT_PERP] = (float)exp(-sh[0]);
    }
}

extern "C" void kernel_launch(void* const* d_in, const int* in_sizes, int n_in,
                              void* d_out, int out_size, void* d_ws, size_t ws_size,
                              hipStream_t stream)
{
    const float* x  = (const float*)d_in[0];
    const float* Wm = (const float*)d_in[1];
    float* out = (float*)d_out;
    float* ws  = (float*)d_ws;

    unsigned short* Wb      = (unsigned short*)(ws + OFF_WB);
    float*          wnorm   = ws + OFF_WNORM;
    float*          enc_sum = ws + OFF_ENCSUM;
    float*          loss_p  = ws + OFF_LOSSP;
    double*         wnd     = (double*)(ws + OFF_WND);

    wprep<<<KCODES / 4, 256, 0, stream>>>(Wm, Wb, wnorm, wnd, enc_sum);
    gemm_topk_quant<<<NROWS / 32, 256, 0, stream>>>(x, Wb, wnorm, wnd, Wm, enc_sum,
                                                    out + OUT_ENC, out + OUT_Q, loss_p);
    finalize_k<<<1, 256, 0, stream>>>(enc_sum, loss_p, out);
}

// Round 11
// 237.442 us; speedup vs baseline: 1.0995x; 1.0026x over previous
//
#include <hip/hip_runtime.h>
#include <math.h>

// Problem constants (fixed by setup_inputs)
#define NROWS 32768   // 32 * 32 * 32
#define DIMS  256
#define KCODES 1024

typedef __attribute__((ext_vector_type(8))) short short8;   // 8 bf16 = 4 VGPRs
typedef __attribute__((ext_vector_type(4))) float f32x4;    // MFMA C/D & stores

// word-level XOR swizzle for the f32 x-bounce tile: carries ALL of hw>>2
// (the load-lane hw-chunk id) into bank bits 2-4. Write side = 2-way (free);
// xs/af b128 reads stay at the 8-lane/16B-group floor.
#define SWZW(hw) ((((hw) >> 2) & 7) << 2)

// ws layout (float offsets)
static const size_t OFF_WB     = 8388608;                // [1024][256] bf16, MFMA-fragment tile order
static const size_t OFF_WNORM  = OFF_WB + 131072;        // [1024] f32
static const size_t OFF_ENCSUM = OFF_WNORM + 1024;       // [1024]
static const size_t OFF_LOSSP  = OFF_ENCSUM + 1024;      // [1024 used]
static const size_t OFF_WND    = OFF_LOSSP + 8192;       // [1024] f64 (2048 floats), 8B aligned

// out layout (float offsets): loss | quantized NCHW | perplexity | encodings
static const size_t OUT_Q    = 1;
static const size_t OUT_PERP = 8388609;
static const size_t OUT_ENC  = 8388610;

__device__ inline unsigned short f2bf(float f) {
    unsigned int u = __float_as_uint(f);
    unsigned int r = u + 0x7FFFu + ((u >> 16) & 1u);   // RNE
    return (unsigned short)(r >> 16);
}

// pack distance (fp32, low 10 mantissa bits cleared) with 10-bit code index.
__device__ inline float packdi(float d, int code) {
    return __uint_as_float((__float_as_uint(d) & 0xFFFFFC00u) | (unsigned)code);
}

// async global->LDS copy, 16B per lane (wave-uniform LDS base + lane*16)
__device__ __forceinline__ void gl_lds16(const void* gsrc, void* ldst) {
    typedef const __attribute__((address_space(1))) unsigned int GU;
    typedef __attribute__((address_space(3))) unsigned int LU;
    __builtin_amdgcn_global_load_lds((GU*)gsrc, (LU*)ldst, 16, 0, 0);
}

// ---------------- W prep: bf16 fragment-order layout + wnorm (f32+f64) ----
__global__ __launch_bounds__(256) void wprep(const float* __restrict__ Wm,
                                             unsigned short* __restrict__ Wb,
                                             float* __restrict__ wnorm,
                                             double* __restrict__ wnormd,
                                             float* __restrict__ enc_sum)
{
    const int r = blockIdx.x * 4 + (threadIdx.x >> 6);
    const int lane = threadIdx.x & 63;
    float4 v = ((const float4*)(Wm + (size_t)r * 256))[lane];
    ushort4 o;
    o.x = f2bf(v.x); o.y = f2bf(v.y); o.z = f2bf(v.z); o.w = f2bf(v.w);
    const int d0 = lane * 4;
    const int kk = d0 >> 5, quad = (d0 >> 3) & 3, jb = d0 & 7;
    const int tt = r >> 4, col = r & 15;
    const size_t idx = (size_t)tt * 4096 + (size_t)((kk * 4 + quad) * 16 + col) * 8 + jb;
    *(ushort4*)(Wb + idx) = o;
    double s = (double)v.x*(double)v.x + (double)v.y*(double)v.y
             + (double)v.z*(double)v.z + (double)v.w*(double)v.w;
    #pragma unroll
    for (int off = 32; off > 0; off >>= 1) s += __shfl_down(s, off);
    if (lane == 0) { wnormd[r] = s; wnorm[r] = (float)s; }
    if (blockIdx.x == 0) {
        #pragma unroll
        for (int q = 0; q < 4; ++q) enc_sum[threadIdx.x * 4 + q] = 0.0f;
    }
}

// ---------------- fused MFMA GEMM + top-k + fp64 refine + enc + quantize + loss ----
// 256 thr = 4 waves, 32 rows/block, grid 1024, LDS 36 KB -> 4 blocks/CU.
// Mappings:
//   MFMA:   wave w: g=w&1 (16-row group), h=w>>1 (512-code half); lane: col,quad
//   refine: row = t>>3 (0..31), q8 = t&7; thread owns dims c*32 + q8*4 + k.
// x ingestion: two-pass coalesced f32 LDS bounce (SWZW swizzle, 2-way writes).
// Main loop (32 iters): dbuf 2x16KB via global_load_lds; split 4+4 MFMA
// chains; med3 exact top-3 insert; in-loop enc row zero-streaming.
// Quantize: single pass, qtile [32 hw][stride 257] — 257 mod 32 = 1 makes
// BOTH the scalar writes (row + 4*q8 + k) and the transposed scalar reads
// (4*hq + j + cl) ~2-way (free). qtile ends @32888 < 33792 (small arrays).
__global__ __launch_bounds__(256, 4) void gemm_topk_quant(
    const float* __restrict__ x, const unsigned short* __restrict__ Wb,
    const float* __restrict__ wnorm, const double* __restrict__ wnd,
    const float* __restrict__ Wm,
    float* __restrict__ enc_sum,
    float* __restrict__ enc,
    float* __restrict__ outq, float* __restrict__ loss_part)
{
    __shared__ __align__(16) char lds[36864];
    // loop: buf0 = lds[0,16K), buf1 = lds[16K,32K); wnLds @ 32K (4 KB)
    // post-loop aliases (phases separated by barriers):
    float*  sCd   = (float*)lds;                 // [96][34] f32 = 13056 B (dump->merge)
    int*    mIdx  = (int*)(lds + 13312);         // [256] -> 14336
    double* rd    = (double*)(lds + 14336);      // [256] f64 -> 16384
    float*  qtile = (float*)lds;                 // [32][257] f32 = 32888 B (epilogue)
    // small arrays live past qtile (wnLds region, dead post-loop):
    double* rnr   = (double*)(lds + 33792);      // [32] f64 -> 34048
    int*    s0    = (int*)(lds + 34048);         // [32] -> 34176
    int*    s1    = (int*)(lds + 34176);         // [32] -> 34304
    float*  sw0   = (float*)(lds + 34304);       // [32] -> 34432
    float*  sw1   = (float*)(lds + 34432);       // [32] -> 34560
    double* sredd = (double*)(lds + 34560);      // [4]  -> 34592
    float*  xbounce = (float*)(lds + 16384);     // [32][128] f32 swizzled, pre-loop (buf1)
    float*  wnLds = (float*)(lds + 32768);       // [1024] f32 (loop only)

    const int t    = threadIdx.x;
    const int wave = t >> 6;
    const int g    = wave & 1;
    const int h    = wave >> 1;
    const int lane = t & 63;
    const int col  = lane & 15;
    const int quad = lane >> 4;
    const int r0   = blockIdx.x * 32;
    const int b    = r0 >> 10;
    const int hw0  = r0 & 1023;
    const float* xblk = x + (size_t)b * 262144 + hw0;   // + d*1024 + hw_local

    const int row = t >> 3;   // refine/epilogue row (hw local), 0..31
    const int q8  = t & 7;    // dim-slice

    // ---- issue prologue B staging (cc=0 -> buf0) + wnorm -> wnLds first ----
    const char* wb_bytes = (const char*)Wb;
    {
        const char* src = wb_bytes + (size_t)(h * 32) * 8192 + g * 4096;
        char* dstl = lds + h * 8192 + g * 4096;
        #pragma unroll
        for (int q = 0; q < 4; ++q)
            gl_lds16(src + q * 1024 + lane * 16, dstl + q * 1024);
        gl_lds16((const char*)wnorm + wave * 1024 + lane * 16,
                 (char*)wnLds + wave * 1024);
    }

    // ---- x ingestion: two-pass coalesced bounce through LDS ----
    float xs[32];
    short8 af[8];
    const int hwq   = t & 7;       // hw chunk (load mapping)
    const int dbase = t >> 3;      // 0..31   (load mapping)
    const int arow  = g * 16 + col;
    #pragma unroll
    for (int h2 = 0; h2 < 2; ++h2) {
        // coalesced global loads: 8 segments of 128B per wave-instr
        float4 xv0, xv1, xv2, xv3;
        {
            const float* xp = xblk + hwq * 4;
            xv0 = *(const float4*)(xp + (size_t)(h2 * 128 +  0 + dbase) * 1024);
            xv1 = *(const float4*)(xp + (size_t)(h2 * 128 + 32 + dbase) * 1024);
            xv2 = *(const float4*)(xp + (size_t)(h2 * 128 + 64 + dbase) * 1024);
            xv3 = *(const float4*)(xp + (size_t)(h2 * 128 + 96 + dbase) * 1024);
        }
        if (h2) __syncthreads();   // pass-0 readers done before overwrite
        // scatter to LDS [hw][dloc], SWZW word-XOR (2-way, free)
        #pragma unroll
        for (int rr = 0; rr < 4; ++rr) {
            const float4 xv = (rr == 0) ? xv0 : (rr == 1) ? xv1 : (rr == 2) ? xv2 : xv3;
            const int dloc = rr * 32 + dbase;
            #pragma unroll
            for (int j = 0; j < 4; ++j) {
                const int hw = hwq * 4 + j;
                const float vj = (j == 0) ? xv.x : (j == 1) ? xv.y : (j == 2) ? xv.z : xv.w;
                xbounce[(hw * 128 + dloc) ^ SWZW(hw)] = vj;
            }
        }
        __syncthreads();
        // xs: 4 b128 reads (dims c*32 + q8*4 .. +3)
        #pragma unroll
        for (int c2 = 0; c2 < 4; ++c2) {
            const int w = (row * 128 + c2 * 32 + q8 * 4) ^ SWZW(row);
            f32x4 v = *(const f32x4*)(xbounce + w);
            xs[(h2 * 4 + c2) * 4 + 0] = v.x;
            xs[(h2 * 4 + c2) * 4 + 1] = v.y;
            xs[(h2 * 4 + c2) * 4 + 2] = v.z;
            xs[(h2 * 4 + c2) * 4 + 3] = v.w;
        }
        // af: direct f32 -> bf16 fragments (rows g*16..g*16+15)
        #pragma unroll
        for (int kk2 = 0; kk2 < 4; ++kk2) {
            const int dloc = kk2 * 32 + quad * 8;
            const int wA = (arow * 128 + dloc) ^ SWZW(arow);
            const int wB = (arow * 128 + dloc + 4) ^ SWZW(arow);
            f32x4 u = *(const f32x4*)(xbounce + wA);
            f32x4 v = *(const f32x4*)(xbounce + wB);
            short8 f;
            f[0] = (short)f2bf(u.x); f[1] = (short)f2bf(u.y);
            f[2] = (short)f2bf(u.z); f[3] = (short)f2bf(u.w);
            f[4] = (short)f2bf(v.x); f[5] = (short)f2bf(v.y);
            f[6] = (short)f2bf(v.z); f[7] = (short)f2bf(v.w);
            af[h2 * 4 + kk2] = f;
        }
    }
    __syncthreads();   // pass-1 reads done; buf0+wnLds staged; cc=0 may write buf1

    float m0[4], m1[4], m2[4];
    #pragma unroll
    for (int r = 0; r < 4; ++r) { m0[r] = 3.4e38f; m1[r] = 3.4e38f; m2[r] = 3.4e38f; }

    const f32x4 zero4 = {0.f, 0.f, 0.f, 0.f};
    for (int cc = 0; cc < 32; ++cc) {
        if (cc < 31) {
            const char* src = wb_bytes + (size_t)(h * 32 + cc + 1) * 8192 + g * 4096;
            char* dstl = lds + ((cc + 1) & 1) * 16384 + h * 8192 + g * 4096;
            #pragma unroll
            for (int q = 0; q < 4; ++q)
                gl_lds16(src + q * 1024 + lane * 16, dstl + q * 1024);
        }
        // zero-stream one encodings row per iteration (coalesced 4 KB)
        *(f32x4*)(enc + (size_t)(r0 + cc) * KCODES + t * 4) = zero4;

        const char* bb = lds + (cc & 1) * 16384 + h * 8192;
        f32x4 acc_a = {0.f, 0.f, 0.f, 0.f};
        f32x4 acc_b = {0.f, 0.f, 0.f, 0.f};
        #pragma unroll
        for (int kk = 0; kk < 4; ++kk) {
            short8 b0 = *(const short8*)(bb + kk * 1024 + lane * 16);
            short8 b1 = *(const short8*)(bb + (kk + 4) * 1024 + lane * 16);
            acc_a = __builtin_amdgcn_mfma_f32_16x16x32_bf16(af[kk], b0, acc_a, 0, 0, 0);
            acc_b = __builtin_amdgcn_mfma_f32_16x16x32_bf16(af[kk + 4], b1, acc_b, 0, 0, 0);
        }
        const int code0 = h * 512 + cc * 16 + col;
        const float wn0 = wnLds[code0];
        #pragma unroll
        for (int r = 0; r < 4; ++r) {
            float pv0 = packdi(fmaf(-2.0f, acc_a[r] + acc_b[r], wn0), code0);
            // exact sorted-3 insert via med3 (3 ops)
            m2[r] = __builtin_amdgcn_fmed3f(m1[r], m2[r], pv0);
            m1[r] = __builtin_amdgcn_fmed3f(m0[r], m1[r], pv0);
            m0[r] = fminf(m0[r], pv0);
        }
        __syncthreads();   // staged data for cc+1 visible; buf[cc&1] reads done
    }

    // ---- dump per-lane candidates, transposed layout [96 slots][34 rows] ----
    #pragma unroll
    for (int r = 0; r < 4; ++r) {
        const int rl = g * 16 + quad * 4 + r;
        const int s  = h * 48 + col * 3;
        sCd[(s + 0) * 34 + rl] = m0[r];
        sCd[(s + 1) * 34 + rl] = m1[r];
        sCd[(s + 2) * 34 + rl] = m2[r];
    }
    __syncthreads();

    // ---- parallel exact top-8 merge: 8 threads/row, 12 slots each ----
    {
        float a0 = 3.4e38f, a1 = 3.4e38f, a2 = 3.4e38f, a3 = 3.4e38f,
              a4 = 3.4e38f, a5 = 3.4e38f, a6 = 3.4e38f, a7 = 3.4e38f;
        #pragma unroll
        for (int i = 0; i < 12; ++i) {
            float d = sCd[(q8 * 12 + i) * 34 + row];
            if (d < a7) {
                a7 = d; float tf;
                if (a7 < a6) { tf = a7; a7 = a6; a6 = tf; }
                if (a6 < a5) { tf = a6; a6 = a5; a5 = tf; }
                if (a5 < a4) { tf = a5; a5 = a4; a4 = tf; }
                if (a4 < a3) { tf = a4; a4 = a3; a3 = tf; }
                if (a3 < a2) { tf = a3; a3 = a2; a2 = tf; }
                if (a2 < a1) { tf = a2; a2 = a1; a1 = tf; }
                if (a1 < a0) { tf = a1; a1 = a0; a0 = tf; }
            }
        }
        // 8 rounds: global min of the 8 heads (values unique via packed code bits)
        float sel = 3.4e38f;
        #pragma unroll
        for (int q = 0; q < 8; ++q) {
            float m = a0;
            m = fminf(m, __shfl_xor(m, 1));
            m = fminf(m, __shfl_xor(m, 2));
            m = fminf(m, __shfl_xor(m, 4));
            if (q8 == q) sel = m;
            if (a0 == m) { a0 = a1; a1 = a2; a2 = a3; a3 = a4;
                           a4 = a5; a5 = a6; a6 = a7; a7 = 3.4e38f; }
        }
        mIdx[row * 8 + q8] = (int)(__float_as_uint(sel) & 1023u);
    }
    __syncthreads();

    // ---- fp64 refine from xs regs: coalesced 128B W reads per row-octet ----
    {
        int cd[8];
        #pragma unroll
        for (int c8 = 0; c8 < 8; ++c8) cd[c8] = mIdx[row * 8 + c8];
        double dot[8];
        #pragma unroll
        for (int c8 = 0; c8 < 8; ++c8) dot[c8] = 0.0;
        double rn = 0.0;
        #pragma unroll
        for (int c = 0; c < 8; ++c) {
            const int d0 = c * 32 + q8 * 4;
            const double x0 = (double)xs[c * 4 + 0];
            const double x1 = (double)xs[c * 4 + 1];
            const double x2 = (double)xs[c * 4 + 2];
            const double x3 = (double)xs[c * 4 + 3];
            rn += x0*x0 + x1*x1 + x2*x2 + x3*x3;
            #pragma unroll
            for (int c8 = 0; c8 < 8; ++c8) {
                const float4 wv = *(const float4*)(Wm + (size_t)cd[c8] * 256 + d0);
                dot[c8] += x0 * (double)wv.x + x1 * (double)wv.y
                         + x2 * (double)wv.z + x3 * (double)wv.w;
            }
        }
        #pragma unroll
        for (int m = 1; m < 8; m <<= 1) {
            #pragma unroll
            for (int c8 = 0; c8 < 8; ++c8) dot[c8] += __shfl_xor(dot[c8], m);
            rn += __shfl_xor(rn, m);
        }
        // static select of this thread's candidate (avoid dynamic reg indexing)
        int myc = 0; double mydot = 0.0;
        #pragma unroll
        for (int c8 = 0; c8 < 8; ++c8)
            if (q8 == c8) { myc = cd[c8]; mydot = dot[c8]; }
        rd[row * 8 + q8] = wnd[myc] - 2.0 * mydot;
        if (q8 == 0) rnr[row] = rn;
    }
    __syncthreads();

    // ---- final per-row top-2 (exact), weights + enc patch stores ----
    if (t < 32) {
        double rn = rnr[t];
        double d0 = 1e300, d1 = 1e300; int b0 = 1 << 30, b1 = 1 << 30;
        #pragma unroll
        for (int q = 0; q < 8; ++q) {
            double d = rd[t * 8 + q];
            int    c = mIdx[t * 8 + q];
            if (d < d0 || (d == d0 && c < b0)) { d1 = d0; b1 = b0; d0 = d; b0 = c; }
            else if (d < d1 || (d == d1 && c < b1)) { d1 = d; b1 = c; }
        }
        double D0 = rn + d0;
        double D1 = rn + d1;
        double inv0 = 1.0 / D0, inv1 = 1.0 / D1;
        double nrm = sqrt(inv0 * inv0 + inv1 * inv1);
        if (nrm < 1e-12) nrm = 1e-12;
        float w0 = (float)(inv0 / nrm);
        float w1 = (float)(inv1 / nrm);
        s0[t] = b0; s1[t] = b1; sw0[t] = w0; sw1[t] = w1;
        atomicAdd(&enc_sum[b0], w0);
        atomicAdd(&enc_sum[b1], w1);
        // patch the two weights into the pre-zeroed encodings row.
        enc[(size_t)(r0 + t) * KCODES + b0] = w0;
        enc[(size_t)(r0 + t) * KCODES + b1] = w1;
    }
    __syncthreads();

    // ---- quantize + loss (from xs) + NCHW write, single full-width pass ----
    double ls = 0.0;
    {
        const int   cA = s0[row], cB = s1[row];
        const float w0 = sw0[row], w1 = sw1[row];
        #pragma unroll
        for (int c = 0; c < 8; ++c) {
            const int dg = c * 32 + q8 * 4;
            const float4 a  = *(const float4*)(Wm + (size_t)cA * 256 + dg);
            const float4 bv = *(const float4*)(Wm + (size_t)cB * 256 + dg);
            float q0 = w0 * a.x + w1 * bv.x;
            float q1 = w0 * a.y + w1 * bv.y;
            float q2 = w0 * a.z + w1 * bv.z;
            float q3 = w0 * a.w + w1 * bv.w;
            float e0 = q0 - xs[c * 4 + 0];
            float e1 = q1 - xs[c * 4 + 1];
            float e2 = q2 - xs[c * 4 + 2];
            float e3 = q3 - xs[c * 4 + 3];
            ls += (double)(e0*e0 + e1*e1 + e2*e2 + e3*e3);
            float* qp = qtile + row * 257 + dg;   // scalar stores: ~2-way, free
            qp[0] = q0; qp[1] = q1; qp[2] = q2; qp[3] = q3;
        }
    }
    __syncthreads();
    #pragma unroll
    for (int p = 0; p < 8; ++p) {
        const int task = p * 256 + t;
        const int cl   = task >> 3;       // channel 0..255
        const int hq   = task & 7;
        f32x4 v;
        v.x = qtile[(hq * 4 + 0) * 257 + cl];
        v.y = qtile[(hq * 4 + 1) * 257 + cl];
        v.z = qtile[(hq * 4 + 2) * 257 + cl];
        v.w = qtile[(hq * 4 + 3) * 257 + cl];
        *(f32x4*)(outq + ((size_t)(b * 256 + cl)) * 1024 + hw0 + hq * 4) = v;
    }

    // ---- block loss partial ----
    #pragma unroll
    for (int off = 32; off > 0; off >>= 1) ls += __shfl_down(ls, off);
    if (lane == 0) sredd[wave] = ls;
    __syncthreads();
    if (t == 0) {
        double s = 0.0;
        #pragma unroll
        for (int w = 0; w < 4; ++w) s += sredd[w];
        loss_part[blockIdx.x] = (float)s;
    }
}

// ---------------- finalize: loss + perplexity ----------------
__global__ __launch_bounds__(256) void finalize_k(const float* __restrict__ enc_sum,
                                                  const float* __restrict__ loss_part,
                                                  float* __restrict__ out)
{
    __shared__ double sh[256];
    const int t = threadIdx.x;
    double ls = 0.0;
    for (int i = t; i < 1024; i += 256) ls += (double)loss_part[i];
    sh[t] = ls; __syncthreads();
    for (int s = 128; s > 0; s >>= 1) { if (t < s) sh[t] += sh[t + s]; __syncthreads(); }
    double loss_sum = sh[0];
    __syncthreads();
    double ps = 0.0;
    for (int k = t; k < KCODES; k += 256) {
        double p = (double)enc_sum[k] / (double)NROWS;
        ps += p * log(p + 1e-10);
    }
    sh[t] = ps; __syncthreads();
    for (int s = 128; s > 0; s >>= 1) { if (t < s) sh[t] += sh[t + s]; __syncthreads(); }
    if (t == 0) {
        out[0]        = (float)(1.25 * loss_sum / 8388608.0);
        out[OUT_PERP] = (float)exp(-sh[0]);
    }
}

extern "C" void kernel_launch(void* const* d_in, const int* in_sizes, int n_in,
                              void* d_out, int out_size, void* d_ws, size_t ws_size,
                              hipStream_t stream)
{
    const float* x  = (const float*)d_in[0];
    const float* Wm = (const float*)d_in[1];
    float* out = (float*)d_out;
    float* ws  = (float*)d_ws;

    unsigned short* Wb      = (unsigned short*)(ws + OFF_WB);
    float*          wnorm   = ws + OFF_WNORM;
    float*          enc_sum = ws + OFF_ENCSUM;
    float*          loss_p  = ws + OFF_LOSSP;
    double*         wnd     = (double*)(ws + OFF_WND);

    wprep<<<KCODES / 4, 256, 0, stream>>>(Wm, Wb, wnorm, wnd, enc_sum);
    gemm_topk_quant<<<NROWS / 32, 256, 0, stream>>>(x, Wb, wnorm, wnd, Wm, enc_sum,
                                                    out + OUT_ENC, out + OUT_Q, loss_p);
    finalize_k<<<1, 256, 0, stream>>>(enc_sum, loss_p, out);
}